// Round 4
// baseline (465.122 us; speedup 1.0000x reference)
//
#include <hip/hip_runtime.h>

#define N_NODES 100000
#define N_EDGES 1600000
#define DIM     128
#define EPS_BN  1e-5f
#define M_TILE  64
#define M_PAD   100032   // 1563 * 64
#define GBLK    1563     // M_PAD / M_TILE
#define LPITCH  136      // LDS pitch in bf16 units (272B = 17*16B, b128-aligned)
#define EGRID   2048     // edge-kernel grid (high occupancy, no LDS)
#define CHUNK   391      // scan chunk: 256*391 = 100096 >= N_NODES

typedef __attribute__((ext_vector_type(8))) short short8;
typedef __attribute__((ext_vector_type(4))) float floatx4;

__device__ __forceinline__ unsigned short f2bf(float f) {   // RNE bf16 bits
    unsigned u = __float_as_uint(f);
    return (unsigned short)((u + 0x7FFF + ((u >> 16) & 1)) >> 16);
}
__device__ __forceinline__ float bf2f(unsigned short b) {
    return __uint_as_float((unsigned)b << 16);
}

// int64 layout => odd int32 words all zero. Wave-uniform result.
__device__ __forceinline__ int detect64(const void* eidx) {
    int v = ((const int*)eidx)[2 * (threadIdx.x & 63) + 1];
    unsigned long long b = __ballot(v != 0);
    return (b == 0ULL) ? 1 : 0;
}
__device__ __forceinline__ int load_row(const void* eidx, int is64, int e) {
    if (is64) return (int)((const long long*)eidx)[e];
    return ((const int*)eidx)[e];
}
__device__ __forceinline__ int load_col(const void* eidx, int is64, int e) {
    if (is64) return (int)((const long long*)eidx)[N_EDGES + e];
    return ((const int*)eidx)[N_EDGES + e];
}

// ---------------------------------------------------------------------------
// init_all: grid-stride xconv (f32 -> bf16); blocks 0/1 transpose W1/W2;
// block 2 zeroes gstats; blocks 3..102 zero deg.
// ---------------------------------------------------------------------------
__global__ __launch_bounds__(256) void init_all(
    const float* __restrict__ x, unsigned short* __restrict__ xb,
    const float* __restrict__ W1, const float* __restrict__ W2,
    unsigned short* __restrict__ W1t, unsigned short* __restrict__ W2t,
    int* __restrict__ deg, float* __restrict__ gstats) {
    int t = threadIdx.x;
    for (int i = blockIdx.x * 256 + t; i < N_NODES * DIM / 4; i += EGRID * 256) {
        float4 v = ((const float4*)x)[i];
        ushort4 o;
        o.x = f2bf(v.x); o.y = f2bf(v.y); o.z = f2bf(v.z); o.w = f2bf(v.w);
        ((ushort4*)xb)[i] = o;
    }
    if (blockIdx.x < 2) {
        const float* W = blockIdx.x ? W2 : W1;
        unsigned short* Wt = blockIdx.x ? W2t : W1t;
        for (int j = t; j < DIM * DIM; j += 256) {
            int k = j >> 7, n = j & 127;
            Wt[n * DIM + k] = f2bf(W[j]);
        }
    } else if (blockIdx.x == 2) {
        if (t < 2 * DIM) gstats[t] = 0.f;
    } else if (blockIdx.x >= 3 && blockIdx.x < 103) {
        int base = (blockIdx.x - 3) * 1024;
#pragma unroll
        for (int k = 0; k < 4; ++k) {
            int i = base + k * 256 + t;
            if (i < N_NODES) deg[i] = 0;
        }
    }
}

// ---------------------------------------------------------------------------
// edge_hist: grid-stride histogram of destination rows. 1.6M atomics over
// 100k L2-resident counters (~16/addr) at full occupancy.
// ---------------------------------------------------------------------------
__global__ __launch_bounds__(256) void edge_hist(const void* eidx,
                                                 int* __restrict__ deg) {
    int is64 = detect64(eidx);
    for (int e = blockIdx.x * 256 + threadIdx.x; e < N_EDGES; e += EGRID * 256)
        atomicAdd(&deg[load_row(eidx, is64, e)], 1);
}

// ---------------------------------------------------------------------------
// scan_part: 256 blocks; block b reduces deg[b*CHUNK .. ) -> bsum[b].
// ---------------------------------------------------------------------------
__global__ __launch_bounds__(256) void scan_part(const int* __restrict__ deg,
                                                 int* __restrict__ bsum) {
    __shared__ int red[256];
    int t = threadIdx.x;
    int n0 = blockIdx.x * CHUNK;
    int s = 0;
    int i0 = n0 + t, i1 = n0 + t + 256;
    if (t < CHUNK && i0 < N_NODES) s += deg[i0];
    if (t + 256 < CHUNK && i1 < N_NODES) s += deg[i1];
    red[t] = s;
    __syncthreads();
    for (int off = 128; off > 0; off >>= 1) {
        if (t < off) red[t] += red[t + off];
        __syncthreads();
    }
    if (t == 0) bsum[blockIdx.x] = red[0];
}

// ---------------------------------------------------------------------------
// scan_write: 256 blocks; block b redundantly scans bsum for its base, then
// scans its 391-chunk in LDS and writes exclusive offsets to rowst AND cur.
// ---------------------------------------------------------------------------
__global__ __launch_bounds__(256) void scan_write(const int* __restrict__ deg,
                                                  const int* __restrict__ bsum,
                                                  int* __restrict__ rowst,
                                                  int* __restrict__ cur) {
    __shared__ int bs[256];
    __shared__ int ch[512];
    int t = threadIdx.x;
    int b = blockIdx.x;
    bs[t] = bsum[t];
    __syncthreads();
    for (int off = 1; off < 256; off <<= 1) {
        int a = (t >= off) ? bs[t - off] : 0;
        __syncthreads();
        bs[t] += a;
        __syncthreads();
    }
    int base = (b == 0) ? 0 : bs[b - 1];
    int n0 = b * CHUNK;
    int v0 = 0, v1 = 0;
    if (t < CHUNK && n0 + t < N_NODES) v0 = deg[n0 + t];
    if (t + 256 < CHUNK && n0 + t + 256 < N_NODES) v1 = deg[n0 + t + 256];
    ch[t] = v0; ch[t + 256] = v1;
    __syncthreads();
    for (int off = 1; off < 512; off <<= 1) {
        int a0 = (t >= off) ? ch[t - off] : 0;
        int a1 = (t + 256 >= off) ? ch[t + 256 - off] : 0;
        __syncthreads();
        ch[t] += a0; ch[t + 256] += a1;
        __syncthreads();
    }
    if (t < CHUNK && n0 + t < N_NODES) {
        int e = base + ch[t] - v0;
        rowst[n0 + t] = e; cur[n0 + t] = e;
    }
    if (t + 256 < CHUNK && n0 + t + 256 < N_NODES) {
        int e = base + ch[t + 256] - v1;
        rowst[n0 + t + 256] = e; cur[n0 + t + 256] = e;
    }
    if (b == 255 && t == 0) rowst[N_NODES] = N_EDGES;
}

// ---------------------------------------------------------------------------
// scatter_cols: grid-stride; pos = cursor++ per destination row; cols is
// 6.4MB (L2-absorbed).
// ---------------------------------------------------------------------------
__global__ __launch_bounds__(256) void scatter_cols(const void* eidx,
                                                    int* __restrict__ cur,
                                                    int* __restrict__ cols) {
    int is64 = detect64(eidx);
    for (int e = blockIdx.x * 256 + threadIdx.x; e < N_EDGES; e += EGRID * 256) {
        int r = load_row(eidx, is64, e);
        int c = load_col(eidx, is64, e);
        int pos = atomicAdd(&cur[r], 1);
        cols[pos] = c;
    }
}

// ---------------------------------------------------------------------------
// Aggregation + residual: Hbf[n] = bf16(xb[n] + sum xb[c]).  (round-0 proven:
// ~60us, 3.7 TB/s = random-256B fabric ceiling.)  One wave per node;
// fully-predicated 16/32-deep load groups, whole neighbor list in flight.
// ---------------------------------------------------------------------------
__global__ __launch_bounds__(256) void agg_kernel(
    const unsigned short* __restrict__ xb,
    const int* __restrict__ row_start, const int* __restrict__ cols,
    unsigned short* __restrict__ Hbf) {
    int wave = threadIdx.x >> 6;
    int lane = threadIdx.x & 63;
    int node = blockIdx.x * 4 + wave;
    const unsigned* xbw = (const unsigned*)xb;     // 64 words per row
    unsigned selfw = xbw[(size_t)node * 64 + lane];
    float2 acc;
    acc.x = __uint_as_float(selfw << 16);
    acc.y = __uint_as_float(selfw & 0xffff0000u);
    int s = row_start[node], e = row_start[node + 1];
    s = __builtin_amdgcn_readfirstlane(s);
    e = __builtin_amdgcn_readfirstlane(e);
    int d = e - s;
    if (d <= 16) {
        unsigned pw[16];
#pragma unroll
        for (int u = 0; u < 16; ++u) {
            int idx = s + u;
            int ci = (idx < e) ? idx : s;              // clamp: dup row, L1 hit
            pw[u] = xbw[(size_t)cols[ci] * 64 + lane];
        }
#pragma unroll
        for (int u = 0; u < 16; ++u) {
            unsigned w = (u < d) ? pw[u] : 0u;         // masked accumulate
            acc.x += __uint_as_float(w << 16);
            acc.y += __uint_as_float(w & 0xffff0000u);
        }
    } else if (d <= 32) {
        unsigned pw[32];
#pragma unroll
        for (int u = 0; u < 32; ++u) {
            int idx = s + u;
            int ci = (idx < e) ? idx : s;
            pw[u] = xbw[(size_t)cols[ci] * 64 + lane];
        }
#pragma unroll
        for (int u = 0; u < 32; ++u) {
            unsigned w = (u < d) ? pw[u] : 0u;
            acc.x += __uint_as_float(w << 16);
            acc.y += __uint_as_float(w & 0xffff0000u);
        }
    } else {
        int j = s;
        for (; j + 16 <= e; j += 16) {
            unsigned pw[16];
#pragma unroll
            for (int u = 0; u < 16; ++u)
                pw[u] = xbw[(size_t)cols[j + u] * 64 + lane];
#pragma unroll
            for (int u = 0; u < 16; ++u) {
                acc.x += __uint_as_float(pw[u] << 16);
                acc.y += __uint_as_float(pw[u] & 0xffff0000u);
            }
        }
        for (; j < e; ++j) {
            unsigned pv = xbw[(size_t)cols[j] * 64 + lane];
            acc.x += __uint_as_float(pv << 16);
            acc.y += __uint_as_float(pv & 0xffff0000u);
        }
    }
    unsigned pack = (unsigned)f2bf(acc.x) | ((unsigned)f2bf(acc.y) << 16);
    ((unsigned*)Hbf)[(size_t)node * 64 + lane] = pack;
}

// ---------------------------------------------------------------------------
// Fused MLP (round-0 proven): h2 = (relu(A@W1+b1))@W2 + b2 per 64-row tile;
// BN stats leave as per-block partials. 52KB LDS -> 3 blocks/CU.
// ---------------------------------------------------------------------------
__global__ __launch_bounds__(256) void mlp_fused(
    const unsigned short* __restrict__ A,    // M_PAD x 128 bf16
    const unsigned short* __restrict__ B1t,  // W1^T bf16 [n][k]
    const unsigned short* __restrict__ B2t,  // W2^T bf16 [n][k]
    const float* __restrict__ bias1, const float* __restrict__ bias2,
    unsigned short* __restrict__ outb,       // M_PAD x 128 bf16
    float* __restrict__ gpart) {             // GBLK x 256 partials
    __shared__ unsigned short As[M_TILE * LPITCH];   // 17408 B
    __shared__ unsigned short Bs[DIM * LPITCH];      // 34816 B
    int t = threadIdx.x;
    int row0 = blockIdx.x * M_TILE;
    int lane = t & 63, wv = t >> 6;
    int m = lane & 15, g = lane >> 4;

#pragma unroll
    for (int i = 0; i < 4; ++i) {
        int ch = t + 256 * i;
        int r = ch >> 4, cc = ch & 15;
        *(uint4*)(&As[r * LPITCH + cc * 8]) =
            *(const uint4*)(&A[(size_t)(row0 + r) * DIM + cc * 8]);
    }
#pragma unroll
    for (int i = 0; i < 8; ++i) {
        int ch = t + 256 * i;
        int n = ch >> 4, cc = ch & 15;
        *(uint4*)(&Bs[n * LPITCH + cc * 8]) =
            *(const uint4*)(&B1t[n * DIM + cc * 8]);
    }
    __syncthreads();

    floatx4 acc1[8] = {};
#pragma unroll
    for (int kc = 0; kc < 4; ++kc) {
        short8 a = *(const short8*)(&As[(wv * 16 + m) * LPITCH + kc * 32 + g * 8]);
#pragma unroll
        for (int tt = 0; tt < 8; ++tt) {
            short8 b = *(const short8*)(&Bs[(tt * 16 + m) * LPITCH + kc * 32 + g * 8]);
            acc1[tt] = __builtin_amdgcn_mfma_f32_16x16x32_bf16(a, b, acc1[tt], 0, 0, 0);
        }
    }
    __syncthreads();

    uint4 wbuf[8];
#pragma unroll
    for (int i = 0; i < 8; ++i) {
        int ch = t + 256 * i;
        int n = ch >> 4, cc = ch & 15;
        wbuf[i] = *(const uint4*)(&B2t[n * DIM + cc * 8]);
    }
#pragma unroll
    for (int tt = 0; tt < 8; ++tt) {
        int col = tt * 16 + m;
        float bv = bias1[col];
#pragma unroll
        for (int j = 0; j < 4; ++j) {
            int rl = wv * 16 + g * 4 + j;
            As[rl * LPITCH + col] = f2bf(fmaxf(acc1[tt][j] + bv, 0.f));
        }
    }
#pragma unroll
    for (int i = 0; i < 8; ++i) {
        int ch = t + 256 * i;
        int n = ch >> 4, cc = ch & 15;
        *(uint4*)(&Bs[n * LPITCH + cc * 8]) = wbuf[i];
    }
    __syncthreads();

    floatx4 acc2[8] = {};
#pragma unroll
    for (int kc = 0; kc < 4; ++kc) {
        short8 a = *(const short8*)(&As[(wv * 16 + m) * LPITCH + kc * 32 + g * 8]);
#pragma unroll
        for (int tt = 0; tt < 8; ++tt) {
            short8 b = *(const short8*)(&Bs[(tt * 16 + m) * LPITCH + kc * 32 + g * 8]);
            acc2[tt] = __builtin_amdgcn_mfma_f32_16x16x32_bf16(a, b, acc2[tt], 0, 0, 0);
        }
    }

    float* csum = (float*)As;
    float* csq = csum + DIM;
    __syncthreads();
    if (t < DIM) { csum[t] = 0.f; csq[t] = 0.f; }
    __syncthreads();
#pragma unroll
    for (int tt = 0; tt < 8; ++tt) {
        int col = tt * 16 + m;
        float bv = bias2[col];
        float s = 0.f, q = 0.f;
#pragma unroll
        for (int j = 0; j < 4; ++j) {
            int row = row0 + wv * 16 + g * 4 + j;
            float v = acc2[tt][j] + bv;
            outb[(size_t)row * DIM + col] = f2bf(v);
            if (row < N_NODES) { s += v; q += v * v; }
        }
        atomicAdd(&csum[col], s);
        atomicAdd(&csq[col], q);
    }
    __syncthreads();
    gpart[(size_t)blockIdx.x * 256 + t] = (t < DIM) ? csum[t] : csq[t - DIM];
}

// ---------------------------------------------------------------------------
// Reduce GBLK x 256 partials -> gstats[256].
// ---------------------------------------------------------------------------
__global__ __launch_bounds__(256) void reduce_stats(
    const float* __restrict__ gpart, float* __restrict__ gstats) {
    int t = threadIdx.x;
    int chunk = (GBLK + 31) / 32;            // 49
    int r0 = blockIdx.x * chunk;
    int r1 = r0 + chunk < GBLK ? r0 + chunk : GBLK;
    float s = 0.f;
    for (int r = r0; r < r1; ++r) s += gpart[(size_t)r * 256 + t];
    atomicAdd(&gstats[t], s);
}

// ---------------------------------------------------------------------------
// BN finalize (redundant per block) + apply.
// ---------------------------------------------------------------------------
__global__ __launch_bounds__(256) void bn_apply(
    const unsigned short* __restrict__ H2, const float* __restrict__ gstats,
    const float* __restrict__ gamma, const float* __restrict__ beta,
    float* __restrict__ out) {
    __shared__ float sc_s[DIM], sh_s[DIM];
    int t = threadIdx.x;
    if (t < DIM) {
        float mean = gstats[t] * (1.0f / N_NODES);
        float m2 = gstats[DIM + t] * (1.0f / N_NODES);
        float var = m2 - mean * mean;
        float inv = rsqrtf(var + EPS_BN);
        float sc = gamma[t] * inv;
        sc_s[t] = sc;
        sh_s[t] = beta[t] - mean * sc;
    }
    __syncthreads();
    int i = blockIdx.x * 256 + t;
    int j4 = (i & 31) * 4;
    ushort4 hv = ((const ushort4*)H2)[i];
    float4 o;
    o.x = bf2f(hv.x) * sc_s[j4 + 0] + sh_s[j4 + 0];
    o.y = bf2f(hv.y) * sc_s[j4 + 1] + sh_s[j4 + 1];
    o.z = bf2f(hv.z) * sc_s[j4 + 2] + sh_s[j4 + 2];
    o.w = bf2f(hv.w) * sc_s[j4 + 3] + sh_s[j4 + 3];
    ((float4*)out)[i] = o;
}

// ---------------------------------------------------------------------------
extern "C" void kernel_launch(void* const* d_in, const int* in_sizes, int n_in,
                              void* d_out, int out_size, void* d_ws,
                              size_t ws_size, hipStream_t stream) {
    (void)in_sizes; (void)n_in; (void)out_size; (void)ws_size;
    const float* x     = (const float*)d_in[0];
    const void*  eidx  = d_in[1];
    const float* W1    = (const float*)d_in[2];
    const float* b1    = (const float*)d_in[3];
    const float* W2    = (const float*)d_in[4];
    const float* b2    = (const float*)d_in[5];
    const float* gamma = (const float*)d_in[6];
    const float* beta  = (const float*)d_in[7];
    float* out = (float*)d_out;

    char* p = (char*)d_ws;
    auto alloc = [&](size_t bytes) {
        char* r = p;
        p += (bytes + 255) & ~(size_t)255;
        return r;
    };
    unsigned short* Hbf  = (unsigned short*)alloc((size_t)M_PAD * DIM * 2); // 25.6MB
    unsigned short* h2bf = (unsigned short*)alloc((size_t)M_PAD * DIM * 2); // 25.6MB
    unsigned short* xb = (unsigned short*)alloc((size_t)N_NODES * DIM * 2);  // 25.6MB
    int*   cols   = (int*)alloc((size_t)(N_EDGES + 64) * 4);                 // 6.4MB
    float* gpart  = (float*)alloc((size_t)GBLK * 256 * 4);                   // 1.6MB
    int*   rowst  = (int*)alloc((size_t)(N_NODES + 1) * 4);
    unsigned short* W1t = (unsigned short*)alloc(DIM * DIM * 2);
    unsigned short* W2t = (unsigned short*)alloc(DIM * DIM * 2);
    float* gstats = (float*)alloc(2 * DIM * 4);
    int*   bsum   = (int*)alloc(256 * 4);
    // deg/cur alias gpart (dead until mlp_fused, which runs after scatter).
    int* deg = (int*)gpart;
    int* cur = deg + 100352;

    init_all<<<EGRID, 256, 0, stream>>>(x, xb, W1, W2, W1t, W2t, deg, gstats);
    edge_hist<<<EGRID, 256, 0, stream>>>(eidx, deg);
    scan_part<<<256, 256, 0, stream>>>(deg, bsum);
    scan_write<<<256, 256, 0, stream>>>(deg, bsum, rowst, cur);
    scatter_cols<<<EGRID, 256, 0, stream>>>(eidx, cur, cols);

    agg_kernel<<<N_NODES / 4, 256, 0, stream>>>(xb, rowst, cols, Hbf);

    mlp_fused<<<GBLK, 256, 0, stream>>>(Hbf, W1t, W2t, b1, b2, h2bf, gpart);
    reduce_stats<<<32, 256, 0, stream>>>(gpart, gstats);
    bn_apply<<<(N_NODES * DIM / 4) / 256, 256, 0, stream>>>(h2bf, gstats,
                                                            gamma, beta, out);
}

// Round 5
// 326.825 us; speedup vs baseline: 1.4232x; 1.4232x over previous
//
#include <hip/hip_runtime.h>

#define N_NODES 100000
#define N_EDGES 1600000
#define DIM     128
#define EPS_BN  1e-5f
#define NB      1024     // buckets
#define NPB     98       // nodes per bucket (1024*98 = 100352 >= 100000)
#define NBLK    1024     // bin_scatter blocks (4/CU co-resident)
#define EPB     1563     // edges per bin_scatter block (1024*1563 >= N_EDGES)
#define CAP     2048     // slot capacity per bucket (mean 1562.5, sigma~40, +12s)
#define M_TILE  64
#define M_PAD   100032   // 1563 * 64
#define GBLK    1563     // M_PAD / M_TILE
#define LPITCH  136      // LDS pitch in bf16 units (272B = 17*16B, b128-aligned)

typedef __attribute__((ext_vector_type(8))) short short8;
typedef __attribute__((ext_vector_type(4))) float floatx4;

__device__ __forceinline__ unsigned short f2bf(float f) {   // RNE bf16 bits
    unsigned u = __float_as_uint(f);
    return (unsigned short)((u + 0x7FFF + ((u >> 16) & 1)) >> 16);
}
__device__ __forceinline__ float bf2f(unsigned short b) {
    return __uint_as_float((unsigned)b << 16);
}

// int64 layout => odd int32 words all zero. Wave-uniform result.
__device__ __forceinline__ int detect64(const void* eidx) {
    int v = ((const int*)eidx)[2 * (threadIdx.x & 63) + 1];
    unsigned long long b = __ballot(v != 0);
    return (b == 0ULL) ? 1 : 0;
}
__device__ __forceinline__ int load_row(const void* eidx, int is64, int e) {
    if (is64) return (int)((const long long*)eidx)[e];
    return ((const int*)eidx)[e];
}
__device__ __forceinline__ int load_col(const void* eidx, int is64, int e) {
    if (is64) return (int)((const long long*)eidx)[N_EDGES + e];
    return ((const int*)eidx)[N_EDGES + e];
}

// ---------------------------------------------------------------------------
// convert_w + workspace init: blocks 0/1 transpose W1/W2 to bf16 [n][k];
// block 2 zeroes bcur (1024) + gstats.
// ---------------------------------------------------------------------------
__global__ void convert_w(const float* __restrict__ W1,
                          const float* __restrict__ W2,
                          unsigned short* __restrict__ W1t,
                          unsigned short* __restrict__ W2t,
                          int* __restrict__ bcur, float* __restrict__ gstats) {
    if (blockIdx.x == 2) {
        int t = threadIdx.x;
        bcur[t] = 0; bcur[t + 256] = 0; bcur[t + 512] = 0; bcur[t + 768] = 0;
        if (t < 2 * DIM) gstats[t] = 0.f;
        return;
    }
    const float* W = blockIdx.x ? W2 : W1;
    unsigned short* Wt = blockIdx.x ? W2t : W1t;
    for (int i = threadIdx.x; i < DIM * DIM; i += 256) {
        int k = i >> 7, n = i & 127;
        Wt[n * DIM + k] = f2bf(W[i]);
    }
}

// ---------------------------------------------------------------------------
// bin_scatter_x: 1024 blocks (4/CU). hist -> LDS scan (1024 buckets) ->
// per-bucket global range claim -> LDS bucket-sorted staging (packed 4B:
// row_local<<24 | col) with precomputed absolute slot addresses -> LINEAR
// copy out. Then grid-stride xconv (f32->bf16). LDS ~= 12KB tables +
// 6.3KB stage + 6.3KB gaddr ~= 25KB -> 4 blocks/CU co-resident.
// ---------------------------------------------------------------------------
__global__ __launch_bounds__(256) void bin_scatter_x(
    const void* eidx, int* bcur, unsigned* __restrict__ slots,
    const float* __restrict__ x, unsigned short* __restrict__ xb) {
    __shared__ int lh[NB];
    __shared__ int lbase[NB];
    __shared__ int loff[NB];
    __shared__ unsigned stage[EPB];
    __shared__ int gaddr[EPB];
    int t = threadIdx.x;
    int is64 = detect64(eidx);
    lh[t] = 0; lh[t + 256] = 0; lh[t + 512] = 0; lh[t + 768] = 0;
    __syncthreads();
    int base = blockIdx.x * EPB;
    int cnt = N_EDGES - base;
    if (cnt > EPB) cnt = EPB;
    if (cnt < 0) cnt = 0;
    for (int i = t; i < cnt; i += 256) {
        int r = load_row(eidx, is64, base + i);
        atomicAdd(&lh[r / NPB], 1);
    }
    __syncthreads();
    // inclusive scan of lh[0..1023] into loff (256 threads, 4 elems each)
    loff[t] = lh[t]; loff[t + 256] = lh[t + 256];
    loff[t + 512] = lh[t + 512]; loff[t + 768] = lh[t + 768];
    __syncthreads();
    for (int off = 1; off < NB; off <<= 1) {
        int a0 = (t >= off) ? loff[t - off] : 0;
        int a1 = (t + 256 >= off) ? loff[t + 256 - off] : 0;
        int a2 = (t + 512 >= off) ? loff[t + 512 - off] : 0;
        int a3 = (t + 768 >= off) ? loff[t + 768 - off] : 0;
        __syncthreads();
        loff[t] += a0; loff[t + 256] += a1;
        loff[t + 512] += a2; loff[t + 768] += a3;
        __syncthreads();
    }
    // claim global ranges, make loff exclusive, reset lh for scatter cursors
#pragma unroll
    for (int q = 0; q < 4; ++q) {
        int i = t + 256 * q;
        int c = lh[i];
        lbase[i] = c ? atomicAdd(&bcur[i], c) : 0;
        loff[i] -= c;
        lh[i] = 0;
    }
    __syncthreads();
    for (int i = t; i < cnt; i += 256) {
        int r = load_row(eidx, is64, base + i);
        int c = load_col(eidx, is64, base + i);
        int b = r / NPB;
        int pos = atomicAdd(&lh[b], 1);
        int idx = loff[b] + pos;
        stage[idx] = ((unsigned)(r - b * NPB) << 24) | (unsigned)c;
        gaddr[idx] = b * CAP + lbase[b] + pos;
    }
    __syncthreads();
    for (int i = t; i < cnt; i += 256)        // linear: runs coalesce to lines
        slots[gaddr[i]] = stage[i];
    // ---- fused xconv: grid-stride f32 -> bf16 (no barrier needed) ----
    for (int i = blockIdx.x * 256 + t; i < N_NODES * DIM / 4; i += NBLK * 256) {
        float4 v = ((const float4*)x)[i];
        ushort4 o;
        o.x = f2bf(v.x); o.y = f2bf(v.y); o.z = f2bf(v.z); o.w = f2bf(v.w);
        ((ushort4*)xb)[i] = o;
    }
}

// ---------------------------------------------------------------------------
// build_csr: 1024 blocks (one per bucket, ~15KB LDS -> 4/CU). In-block
// redundant scan of bucket counts, then LDS hist/scan/scatter of this
// bucket's packed pairs, coalesced out.
// ---------------------------------------------------------------------------
__global__ __launch_bounds__(256) void build_csr(const unsigned* __restrict__ slots,
                                                 const int* __restrict__ bcnt,
                                                 int* __restrict__ rowst,
                                                 int* __restrict__ cols) {
    __shared__ int tmp[NB];
    __shared__ int hist[256];
    __shared__ int excl[256];
    __shared__ int cur[256];
    __shared__ int colbuf[CAP];
    int t = threadIdx.x;
    int b = blockIdx.x;
    // inclusive scan of bcnt[0..1023] into tmp
    tmp[t] = bcnt[t]; tmp[t + 256] = bcnt[t + 256];
    tmp[t + 512] = bcnt[t + 512]; tmp[t + 768] = bcnt[t + 768];
    __syncthreads();
    for (int off = 1; off < NB; off <<= 1) {
        int a0 = (t >= off) ? tmp[t - off] : 0;
        int a1 = (t + 256 >= off) ? tmp[t + 256 - off] : 0;
        int a2 = (t + 512 >= off) ? tmp[t + 512 - off] : 0;
        int a3 = (t + 768 >= off) ? tmp[t + 768 - off] : 0;
        __syncthreads();
        tmp[t] += a0; tmp[t + 256] += a1;
        tmp[t + 512] += a2; tmp[t + 768] += a3;
        __syncthreads();
    }
    int cnt = bcnt[b];
    int s = tmp[b] - cnt;                     // exclusive start
    int node0 = b * NPB;
    int nn = N_NODES - node0;
    if (nn > NPB) nn = NPB;
    if (nn < 0) nn = 0;
    const unsigned* pairs = slots + (size_t)b * CAP;
    hist[t] = 0;
    if (b == NB - 1 && t == 0) rowst[N_NODES] = N_EDGES;
    __syncthreads();
    for (int i = t; i < cnt; i += 256)
        atomicAdd(&hist[(int)(pairs[i] >> 24)], 1);
    __syncthreads();
    int v = hist[t];
    excl[t] = v;
    __syncthreads();
    for (int off = 1; off < 256; off <<= 1) {
        int a = (t >= off) ? excl[t - off] : 0;
        __syncthreads();
        excl[t] += a;
        __syncthreads();
    }
    int ex = excl[t] - v;
    if (t < nn) rowst[node0 + t] = s + ex;
    cur[t] = ex;
    __syncthreads();
    for (int i = t; i < cnt; i += 256) {
        unsigned pr = pairs[i];
        int pos = atomicAdd(&cur[pr >> 24], 1);
        colbuf[pos] = (int)(pr & 0xFFFFFFu);
    }
    __syncthreads();
    for (int i = t; i < cnt; i += 256) cols[s + i] = colbuf[i];
}

// ---------------------------------------------------------------------------
// Aggregation + residual: Hbf[n] = bf16(xb[n] + sum xb[c]).  (round-0 proven:
// ~60us, 3.7 TB/s = random-256B fabric ceiling.)  One wave per node;
// fully-predicated 16/32-deep load groups, whole neighbor list in flight.
// ---------------------------------------------------------------------------
__global__ __launch_bounds__(256) void agg_kernel(
    const unsigned short* __restrict__ xb,
    const int* __restrict__ row_start, const int* __restrict__ cols,
    unsigned short* __restrict__ Hbf) {
    int wave = threadIdx.x >> 6;
    int lane = threadIdx.x & 63;
    int node = blockIdx.x * 4 + wave;
    const unsigned* xbw = (const unsigned*)xb;     // 64 words per row
    unsigned selfw = xbw[(size_t)node * 64 + lane];
    float2 acc;
    acc.x = __uint_as_float(selfw << 16);
    acc.y = __uint_as_float(selfw & 0xffff0000u);
    int s = row_start[node], e = row_start[node + 1];
    s = __builtin_amdgcn_readfirstlane(s);
    e = __builtin_amdgcn_readfirstlane(e);
    int d = e - s;
    if (d <= 16) {
        unsigned pw[16];
#pragma unroll
        for (int u = 0; u < 16; ++u) {
            int idx = s + u;
            int ci = (idx < e) ? idx : s;              // clamp: dup row, L1 hit
            pw[u] = xbw[(size_t)cols[ci] * 64 + lane];
        }
#pragma unroll
        for (int u = 0; u < 16; ++u) {
            unsigned w = (u < d) ? pw[u] : 0u;         // masked accumulate
            acc.x += __uint_as_float(w << 16);
            acc.y += __uint_as_float(w & 0xffff0000u);
        }
    } else if (d <= 32) {
        unsigned pw[32];
#pragma unroll
        for (int u = 0; u < 32; ++u) {
            int idx = s + u;
            int ci = (idx < e) ? idx : s;
            pw[u] = xbw[(size_t)cols[ci] * 64 + lane];
        }
#pragma unroll
        for (int u = 0; u < 32; ++u) {
            unsigned w = (u < d) ? pw[u] : 0u;
            acc.x += __uint_as_float(w << 16);
            acc.y += __uint_as_float(w & 0xffff0000u);
        }
    } else {
        int j = s;
        for (; j + 16 <= e; j += 16) {
            unsigned pw[16];
#pragma unroll
            for (int u = 0; u < 16; ++u)
                pw[u] = xbw[(size_t)cols[j + u] * 64 + lane];
#pragma unroll
            for (int u = 0; u < 16; ++u) {
                acc.x += __uint_as_float(pw[u] << 16);
                acc.y += __uint_as_float(pw[u] & 0xffff0000u);
            }
        }
        for (; j < e; ++j) {
            unsigned pv = xbw[(size_t)cols[j] * 64 + lane];
            acc.x += __uint_as_float(pv << 16);
            acc.y += __uint_as_float(pv & 0xffff0000u);
        }
    }
    unsigned pack = (unsigned)f2bf(acc.x) | ((unsigned)f2bf(acc.y) << 16);
    ((unsigned*)Hbf)[(size_t)node * 64 + lane] = pack;
}

// ---------------------------------------------------------------------------
// Fused MLP (round-0 proven): h2 = (relu(A@W1+b1))@W2 + b2 per 64-row tile;
// BN stats leave as per-block partials. 52KB LDS -> 3 blocks/CU.
// ---------------------------------------------------------------------------
__global__ __launch_bounds__(256) void mlp_fused(
    const unsigned short* __restrict__ A,    // M_PAD x 128 bf16
    const unsigned short* __restrict__ B1t,  // W1^T bf16 [n][k]
    const unsigned short* __restrict__ B2t,  // W2^T bf16 [n][k]
    const float* __restrict__ bias1, const float* __restrict__ bias2,
    unsigned short* __restrict__ outb,       // M_PAD x 128 bf16
    float* __restrict__ gpart) {             // GBLK x 256 partials
    __shared__ unsigned short As[M_TILE * LPITCH];   // 17408 B
    __shared__ unsigned short Bs[DIM * LPITCH];      // 34816 B
    int t = threadIdx.x;
    int row0 = blockIdx.x * M_TILE;
    int lane = t & 63, wv = t >> 6;
    int m = lane & 15, g = lane >> 4;

#pragma unroll
    for (int i = 0; i < 4; ++i) {
        int ch = t + 256 * i;
        int r = ch >> 4, cc = ch & 15;
        *(uint4*)(&As[r * LPITCH + cc * 8]) =
            *(const uint4*)(&A[(size_t)(row0 + r) * DIM + cc * 8]);
    }
#pragma unroll
    for (int i = 0; i < 8; ++i) {
        int ch = t + 256 * i;
        int n = ch >> 4, cc = ch & 15;
        *(uint4*)(&Bs[n * LPITCH + cc * 8]) =
            *(const uint4*)(&B1t[n * DIM + cc * 8]);
    }
    __syncthreads();

    floatx4 acc1[8] = {};
#pragma unroll
    for (int kc = 0; kc < 4; ++kc) {
        short8 a = *(const short8*)(&As[(wv * 16 + m) * LPITCH + kc * 32 + g * 8]);
#pragma unroll
        for (int tt = 0; tt < 8; ++tt) {
            short8 b = *(const short8*)(&Bs[(tt * 16 + m) * LPITCH + kc * 32 + g * 8]);
            acc1[tt] = __builtin_amdgcn_mfma_f32_16x16x32_bf16(a, b, acc1[tt], 0, 0, 0);
        }
    }
    __syncthreads();

    uint4 wbuf[8];
#pragma unroll
    for (int i = 0; i < 8; ++i) {
        int ch = t + 256 * i;
        int n = ch >> 4, cc = ch & 15;
        wbuf[i] = *(const uint4*)(&B2t[n * DIM + cc * 8]);
    }
#pragma unroll
    for (int tt = 0; tt < 8; ++tt) {
        int col = tt * 16 + m;
        float bv = bias1[col];
#pragma unroll
        for (int j = 0; j < 4; ++j) {
            int rl = wv * 16 + g * 4 + j;
            As[rl * LPITCH + col] = f2bf(fmaxf(acc1[tt][j] + bv, 0.f));
        }
    }
#pragma unroll
    for (int i = 0; i < 8; ++i) {
        int ch = t + 256 * i;
        int n = ch >> 4, cc = ch & 15;
        *(uint4*)(&Bs[n * LPITCH + cc * 8]) = wbuf[i];
    }
    __syncthreads();

    floatx4 acc2[8] = {};
#pragma unroll
    for (int kc = 0; kc < 4; ++kc) {
        short8 a = *(const short8*)(&As[(wv * 16 + m) * LPITCH + kc * 32 + g * 8]);
#pragma unroll
        for (int tt = 0; tt < 8; ++tt) {
            short8 b = *(const short8*)(&Bs[(tt * 16 + m) * LPITCH + kc * 32 + g * 8]);
            acc2[tt] = __builtin_amdgcn_mfma_f32_16x16x32_bf16(a, b, acc2[tt], 0, 0, 0);
        }
    }

    float* csum = (float*)As;
    float* csq = csum + DIM;
    __syncthreads();
    if (t < DIM) { csum[t] = 0.f; csq[t] = 0.f; }
    __syncthreads();
#pragma unroll
    for (int tt = 0; tt < 8; ++tt) {
        int col = tt * 16 + m;
        float bv = bias2[col];
        float s = 0.f, q = 0.f;
#pragma unroll
        for (int j = 0; j < 4; ++j) {
            int row = row0 + wv * 16 + g * 4 + j;
            float v = acc2[tt][j] + bv;
            outb[(size_t)row * DIM + col] = f2bf(v);
            if (row < N_NODES) { s += v; q += v * v; }
        }
        atomicAdd(&csum[col], s);
        atomicAdd(&csq[col], q);
    }
    __syncthreads();
    gpart[(size_t)blockIdx.x * 256 + t] = (t < DIM) ? csum[t] : csq[t - DIM];
}

// ---------------------------------------------------------------------------
// Reduce GBLK x 256 partials -> gstats[256].
// ---------------------------------------------------------------------------
__global__ __launch_bounds__(256) void reduce_stats(
    const float* __restrict__ gpart, float* __restrict__ gstats) {
    int t = threadIdx.x;
    int chunk = (GBLK + 31) / 32;            // 49
    int r0 = blockIdx.x * chunk;
    int r1 = r0 + chunk < GBLK ? r0 + chunk : GBLK;
    float s = 0.f;
    for (int r = r0; r < r1; ++r) s += gpart[(size_t)r * 256 + t];
    atomicAdd(&gstats[t], s);
}

// ---------------------------------------------------------------------------
// BN finalize (redundant per block) + apply.
// ---------------------------------------------------------------------------
__global__ __launch_bounds__(256) void bn_apply(
    const unsigned short* __restrict__ H2, const float* __restrict__ gstats,
    const float* __restrict__ gamma, const float* __restrict__ beta,
    float* __restrict__ out) {
    __shared__ float sc_s[DIM], sh_s[DIM];
    int t = threadIdx.x;
    if (t < DIM) {
        float mean = gstats[t] * (1.0f / N_NODES);
        float m2 = gstats[DIM + t] * (1.0f / N_NODES);
        float var = m2 - mean * mean;
        float inv = rsqrtf(var + EPS_BN);
        float sc = gamma[t] * inv;
        sc_s[t] = sc;
        sh_s[t] = beta[t] - mean * sc;
    }
    __syncthreads();
    int i = blockIdx.x * 256 + t;
    int j4 = (i & 31) * 4;
    ushort4 hv = ((const ushort4*)H2)[i];
    float4 o;
    o.x = bf2f(hv.x) * sc_s[j4 + 0] + sh_s[j4 + 0];
    o.y = bf2f(hv.y) * sc_s[j4 + 1] + sh_s[j4 + 1];
    o.z = bf2f(hv.z) * sc_s[j4 + 2] + sh_s[j4 + 2];
    o.w = bf2f(hv.w) * sc_s[j4 + 3] + sh_s[j4 + 3];
    ((float4*)out)[i] = o;
}

// ---------------------------------------------------------------------------
extern "C" void kernel_launch(void* const* d_in, const int* in_sizes, int n_in,
                              void* d_out, int out_size, void* d_ws,
                              size_t ws_size, hipStream_t stream) {
    (void)in_sizes; (void)n_in; (void)out_size; (void)ws_size;
    const float* x     = (const float*)d_in[0];
    const void*  eidx  = d_in[1];
    const float* W1    = (const float*)d_in[2];
    const float* b1    = (const float*)d_in[3];
    const float* W2    = (const float*)d_in[4];
    const float* b2    = (const float*)d_in[5];
    const float* gamma = (const float*)d_in[6];
    const float* beta  = (const float*)d_in[7];
    float* out = (float*)d_out;

    char* p = (char*)d_ws;
    auto alloc = [&](size_t bytes) {
        char* r = p;
        p += (bytes + 255) & ~(size_t)255;
        return r;
    };
    unsigned short* Hbf  = (unsigned short*)alloc((size_t)M_PAD * DIM * 2); // 25.6MB
    unsigned short* h2bf = (unsigned short*)alloc((size_t)M_PAD * DIM * 2); // 25.6MB
    // slots (8.4MB, packed 4B) alias h2bf: dead before mlp writes h2
    unsigned* slots = (unsigned*)h2bf;
    unsigned short* xb = (unsigned short*)alloc((size_t)N_NODES * DIM * 2);  // 25.6MB
    int*   cols   = (int*)alloc((size_t)(N_EDGES + 64) * 4);                 // 6.4MB
    float* gpart  = (float*)alloc((size_t)GBLK * 256 * 4);                   // 1.6MB
    int*   rowst  = (int*)alloc((size_t)(N_NODES + 1) * 4);
    int*   bcur   = (int*)alloc(NB * 4);
    unsigned short* W1t = (unsigned short*)alloc(DIM * DIM * 2);
    unsigned short* W2t = (unsigned short*)alloc(DIM * DIM * 2);
    float* gstats = (float*)alloc(2 * DIM * 4);

    convert_w<<<3, 256, 0, stream>>>(W1, W2, W1t, W2t, bcur, gstats);
    bin_scatter_x<<<NBLK, 256, 0, stream>>>(eidx, bcur, slots, x, xb);
    build_csr<<<NB, 256, 0, stream>>>(slots, bcur, rowst, cols);

    agg_kernel<<<N_NODES / 4, 256, 0, stream>>>(xb, rowst, cols, Hbf);

    mlp_fused<<<GBLK, 256, 0, stream>>>(Hbf, W1t, W2t, b1, b2, h2bf, gpart);
    reduce_stats<<<32, 256, 0, stream>>>(gpart, gstats);
    bn_apply<<<(N_NODES * DIM / 4) / 256, 256, 0, stream>>>(h2bf, gstats,
                                                            gamma, beta, out);
}

// Round 6
// 290.167 us; speedup vs baseline: 1.6029x; 1.1263x over previous
//
#include <hip/hip_runtime.h>

#define N_NODES 100000
#define N_EDGES 1600000
#define DIM     128
#define EPS_BN  1e-5f
#define NB      512      // buckets
#define NPB     196      // nodes per bucket (512*196 >= 100000)
#define NBLK    256      // bin_scatter blocks
#define EPB     6250     // edges per bin_scatter block (256*6250 == N_EDGES)
#define CAP     4096     // slot capacity per bucket (mean 3125, sigma~56)
#define M_TILE  64
#define M_PAD   100032   // 1563 * 64
#define GBLK    1563     // M_PAD / M_TILE
#define LPITCH  136      // LDS pitch in bf16 units (272B = 17*16B, b128-aligned)

typedef __attribute__((ext_vector_type(8))) short short8;
typedef __attribute__((ext_vector_type(4))) float floatx4;

__device__ __forceinline__ unsigned short f2bf(float f) {   // RNE bf16 bits
    unsigned u = __float_as_uint(f);
    return (unsigned short)((u + 0x7FFF + ((u >> 16) & 1)) >> 16);
}
__device__ __forceinline__ float bf2f(unsigned short b) {
    return __uint_as_float((unsigned)b << 16);
}

// int64 layout => odd int32 words all zero. Wave-uniform result.
__device__ __forceinline__ int detect64(const void* eidx) {
    int v = ((const int*)eidx)[2 * (threadIdx.x & 63) + 1];
    unsigned long long b = __ballot(v != 0);
    return (b == 0ULL) ? 1 : 0;
}
__device__ __forceinline__ int load_row(const void* eidx, int is64, int e) {
    if (is64) return (int)((const long long*)eidx)[e];
    return ((const int*)eidx)[e];
}
__device__ __forceinline__ int load_col(const void* eidx, int is64, int e) {
    if (is64) return (int)((const long long*)eidx)[N_EDGES + e];
    return ((const int*)eidx)[N_EDGES + e];
}

// ---------------------------------------------------------------------------
// convert_w + workspace init: blocks 0/1 transpose W1/W2 to bf16 [n][k];
// block 2 zeroes bcur + gstats.
// ---------------------------------------------------------------------------
__global__ void convert_w(const float* __restrict__ W1,
                          const float* __restrict__ W2,
                          unsigned short* __restrict__ W1t,
                          unsigned short* __restrict__ W2t,
                          int* __restrict__ bcur, float* __restrict__ gstats) {
    if (blockIdx.x == 2) {
        int t = threadIdx.x;
        bcur[t] = 0;
        bcur[256 + t] = 0;
        if (t < 2 * DIM) gstats[t] = 0.f;
        return;
    }
    const float* W = blockIdx.x ? W2 : W1;
    unsigned short* Wt = blockIdx.x ? W2t : W1t;
    for (int i = threadIdx.x; i < DIM * DIM; i += 256) {
        int k = i >> 7, n = i & 127;
        Wt[n * DIM + k] = f2bf(W[i]);
    }
}

// ---------------------------------------------------------------------------
// bin_scatter_x: 256 blocks x 1024 threads (16 waves/block = 4 waves/SIMD;
// was 1 wave/SIMD at 256 threads -> latency phases 4x faster). hist -> LDS
// scan (512 buckets, threads 0..511) -> per-bucket global range claim ->
// LDS bucket-sorted staging (packed 4B: row_local<<24 | col) -> LINEAR copy
// out (~12 contiguous slots per bucket per block coalesce into lines).
// Then grid-stride xconv. LDS: 3*2KB + 25KB stage + 25KB gaddr = 56KB.
// ---------------------------------------------------------------------------
__global__ __launch_bounds__(1024) void bin_scatter_x(
    const void* eidx, int* bcur, unsigned* __restrict__ slots,
    const float* __restrict__ x, unsigned short* __restrict__ xb) {
    __shared__ int lh[NB];
    __shared__ int lbase[NB];
    __shared__ int loff[NB];
    __shared__ unsigned stage[EPB];
    __shared__ int gaddr[EPB];
    int t = threadIdx.x;
    int is64 = detect64(eidx);
    if (t < NB) lh[t] = 0;
    __syncthreads();
    int base = blockIdx.x * EPB;
    for (int i = t; i < EPB; i += 1024) {
        int r = load_row(eidx, is64, base + i);
        atomicAdd(&lh[r / NPB], 1);
    }
    __syncthreads();
    // inclusive scan of lh[0..511] into loff (threads 0..511, 1 elem each)
    if (t < NB) loff[t] = lh[t];
    __syncthreads();
    for (int off = 1; off < NB; off <<= 1) {
        int a = (t >= off && t < NB) ? loff[t - off] : 0;
        __syncthreads();
        if (t < NB) loff[t] += a;
        __syncthreads();
    }
    // claim global ranges, make loff exclusive, reset lh for scatter cursors
    if (t < NB) {
        int c = lh[t];
        lbase[t] = c ? atomicAdd(&bcur[t], c) : 0;
        loff[t] -= c;
        lh[t] = 0;
    }
    __syncthreads();
    for (int i = t; i < EPB; i += 1024) {
        int r = load_row(eidx, is64, base + i);
        int c = load_col(eidx, is64, base + i);
        int b = r / NPB;
        int pos = atomicAdd(&lh[b], 1);
        int idx = loff[b] + pos;
        stage[idx] = ((unsigned)(r - b * NPB) << 24) | (unsigned)c;
        gaddr[idx] = b * CAP + lbase[b] + pos;
    }
    __syncthreads();
    for (int i = t; i < EPB; i += 1024)       // linear: runs coalesce to lines
        slots[gaddr[i]] = stage[i];
    // ---- fused xconv: grid-stride f32 -> bf16 (no barrier needed) ----
    for (int i = blockIdx.x * 1024 + t; i < N_NODES * DIM / 4; i += NBLK * 1024) {
        float4 v = ((const float4*)x)[i];
        ushort4 o;
        o.x = f2bf(v.x); o.y = f2bf(v.y); o.z = f2bf(v.z); o.w = f2bf(v.w);
        ((ushort4*)xb)[i] = o;
    }
}

// ---------------------------------------------------------------------------
// build_csr: 512 blocks x 1024 threads (2 blocks/CU = 8 waves/SIMD). In-block
// redundant scan of bucket counts, then LDS hist/scan/scatter of this
// bucket's packed pairs, coalesced out. LDS ~= 21.5KB.
// ---------------------------------------------------------------------------
__global__ __launch_bounds__(1024) void build_csr(const unsigned* __restrict__ slots,
                                                  const int* __restrict__ bcnt,
                                                  int* __restrict__ rowst,
                                                  int* __restrict__ cols) {
    __shared__ int tmp[NB];
    __shared__ int hist[256];
    __shared__ int excl[256];
    __shared__ int cur[256];
    __shared__ int colbuf[CAP];
    int t = threadIdx.x;
    int b = blockIdx.x;
    // inclusive scan of bcnt[0..511] into tmp (threads 0..511)
    if (t < NB) tmp[t] = bcnt[t];
    __syncthreads();
    for (int off = 1; off < NB; off <<= 1) {
        int a = (t >= off && t < NB) ? tmp[t - off] : 0;
        __syncthreads();
        if (t < NB) tmp[t] += a;
        __syncthreads();
    }
    int cnt = bcnt[b];
    int s = tmp[b] - cnt;                     // exclusive start
    int node0 = b * NPB;
    int nn = N_NODES - node0;
    if (nn > NPB) nn = NPB;
    const unsigned* pairs = slots + (size_t)b * CAP;
    if (t < 256) hist[t] = 0;
    if (b == NB - 1 && t == 0) rowst[N_NODES] = N_EDGES;
    __syncthreads();
    for (int i = t; i < cnt; i += 1024)
        atomicAdd(&hist[(int)(pairs[i] >> 24)], 1);
    __syncthreads();
    int v = (t < 256) ? hist[t] : 0;
    if (t < 256) excl[t] = v;
    __syncthreads();
    for (int off = 1; off < 256; off <<= 1) {
        int a = (t >= off && t < 256) ? excl[t - off] : 0;
        __syncthreads();
        if (t < 256) excl[t] += a;
        __syncthreads();
    }
    if (t < 256) {
        int ex = excl[t] - v;
        if (t < nn) rowst[node0 + t] = s + ex;
        cur[t] = ex;
    }
    __syncthreads();
    for (int i = t; i < cnt; i += 1024) {
        unsigned pr = pairs[i];
        int pos = atomicAdd(&cur[pr >> 24], 1);
        colbuf[pos] = (int)(pr & 0xFFFFFFu);
    }
    __syncthreads();
    for (int i = t; i < cnt; i += 1024) cols[s + i] = colbuf[i];
}

// ---------------------------------------------------------------------------
// Aggregation + residual: Hbf[n] = bf16(xb[n] + sum xb[c]).  (round-0 proven:
// ~60us, 3.7 TB/s = random-256B fabric ceiling.)  One wave per node;
// fully-predicated 16/32-deep load groups, whole neighbor list in flight.
// ---------------------------------------------------------------------------
__global__ __launch_bounds__(256) void agg_kernel(
    const unsigned short* __restrict__ xb,
    const int* __restrict__ row_start, const int* __restrict__ cols,
    unsigned short* __restrict__ Hbf) {
    int wave = threadIdx.x >> 6;
    int lane = threadIdx.x & 63;
    int node = blockIdx.x * 4 + wave;
    const unsigned* xbw = (const unsigned*)xb;     // 64 words per row
    unsigned selfw = xbw[(size_t)node * 64 + lane];
    float2 acc;
    acc.x = __uint_as_float(selfw << 16);
    acc.y = __uint_as_float(selfw & 0xffff0000u);
    int s = row_start[node], e = row_start[node + 1];
    s = __builtin_amdgcn_readfirstlane(s);
    e = __builtin_amdgcn_readfirstlane(e);
    int d = e - s;
    if (d <= 16) {
        unsigned pw[16];
#pragma unroll
        for (int u = 0; u < 16; ++u) {
            int idx = s + u;
            int ci = (idx < e) ? idx : s;              // clamp: dup row, L1 hit
            pw[u] = xbw[(size_t)cols[ci] * 64 + lane];
        }
#pragma unroll
        for (int u = 0; u < 16; ++u) {
            unsigned w = (u < d) ? pw[u] : 0u;         // masked accumulate
            acc.x += __uint_as_float(w << 16);
            acc.y += __uint_as_float(w & 0xffff0000u);
        }
    } else if (d <= 32) {
        unsigned pw[32];
#pragma unroll
        for (int u = 0; u < 32; ++u) {
            int idx = s + u;
            int ci = (idx < e) ? idx : s;
            pw[u] = xbw[(size_t)cols[ci] * 64 + lane];
        }
#pragma unroll
        for (int u = 0; u < 32; ++u) {
            unsigned w = (u < d) ? pw[u] : 0u;
            acc.x += __uint_as_float(w << 16);
            acc.y += __uint_as_float(w & 0xffff0000u);
        }
    } else {
        int j = s;
        for (; j + 16 <= e; j += 16) {
            unsigned pw[16];
#pragma unroll
            for (int u = 0; u < 16; ++u)
                pw[u] = xbw[(size_t)cols[j + u] * 64 + lane];
#pragma unroll
            for (int u = 0; u < 16; ++u) {
                acc.x += __uint_as_float(pw[u] << 16);
                acc.y += __uint_as_float(pw[u] & 0xffff0000u);
            }
        }
        for (; j < e; ++j) {
            unsigned pv = xbw[(size_t)cols[j] * 64 + lane];
            acc.x += __uint_as_float(pv << 16);
            acc.y += __uint_as_float(pv & 0xffff0000u);
        }
    }
    unsigned pack = (unsigned)f2bf(acc.x) | ((unsigned)f2bf(acc.y) << 16);
    ((unsigned*)Hbf)[(size_t)node * 64 + lane] = pack;
}

// ---------------------------------------------------------------------------
// Fused MLP (round-0 proven): h2 = (relu(A@W1+b1))@W2 + b2 per 64-row tile;
// BN stats leave as per-block partials. 52KB LDS -> 3 blocks/CU.
// ---------------------------------------------------------------------------
__global__ __launch_bounds__(256) void mlp_fused(
    const unsigned short* __restrict__ A,    // M_PAD x 128 bf16
    const unsigned short* __restrict__ B1t,  // W1^T bf16 [n][k]
    const unsigned short* __restrict__ B2t,  // W2^T bf16 [n][k]
    const float* __restrict__ bias1, const float* __restrict__ bias2,
    unsigned short* __restrict__ outb,       // M_PAD x 128 bf16
    float* __restrict__ gpart) {             // GBLK x 256 partials
    __shared__ unsigned short As[M_TILE * LPITCH];   // 17408 B
    __shared__ unsigned short Bs[DIM * LPITCH];      // 34816 B
    int t = threadIdx.x;
    int row0 = blockIdx.x * M_TILE;
    int lane = t & 63, wv = t >> 6;
    int m = lane & 15, g = lane >> 4;

#pragma unroll
    for (int i = 0; i < 4; ++i) {
        int ch = t + 256 * i;
        int r = ch >> 4, cc = ch & 15;
        *(uint4*)(&As[r * LPITCH + cc * 8]) =
            *(const uint4*)(&A[(size_t)(row0 + r) * DIM + cc * 8]);
    }
#pragma unroll
    for (int i = 0; i < 8; ++i) {
        int ch = t + 256 * i;
        int n = ch >> 4, cc = ch & 15;
        *(uint4*)(&Bs[n * LPITCH + cc * 8]) =
            *(const uint4*)(&B1t[n * DIM + cc * 8]);
    }
    __syncthreads();

    floatx4 acc1[8] = {};
#pragma unroll
    for (int kc = 0; kc < 4; ++kc) {
        short8 a = *(const short8*)(&As[(wv * 16 + m) * LPITCH + kc * 32 + g * 8]);
#pragma unroll
        for (int tt = 0; tt < 8; ++tt) {
            short8 b = *(const short8*)(&Bs[(tt * 16 + m) * LPITCH + kc * 32 + g * 8]);
            acc1[tt] = __builtin_amdgcn_mfma_f32_16x16x32_bf16(a, b, acc1[tt], 0, 0, 0);
        }
    }
    __syncthreads();

    uint4 wbuf[8];
#pragma unroll
    for (int i = 0; i < 8; ++i) {
        int ch = t + 256 * i;
        int n = ch >> 4, cc = ch & 15;
        wbuf[i] = *(const uint4*)(&B2t[n * DIM + cc * 8]);
    }
#pragma unroll
    for (int tt = 0; tt < 8; ++tt) {
        int col = tt * 16 + m;
        float bv = bias1[col];
#pragma unroll
        for (int j = 0; j < 4; ++j) {
            int rl = wv * 16 + g * 4 + j;
            As[rl * LPITCH + col] = f2bf(fmaxf(acc1[tt][j] + bv, 0.f));
        }
    }
#pragma unroll
    for (int i = 0; i < 8; ++i) {
        int ch = t + 256 * i;
        int n = ch >> 4, cc = ch & 15;
        *(uint4*)(&Bs[n * LPITCH + cc * 8]) = wbuf[i];
    }
    __syncthreads();

    floatx4 acc2[8] = {};
#pragma unroll
    for (int kc = 0; kc < 4; ++kc) {
        short8 a = *(const short8*)(&As[(wv * 16 + m) * LPITCH + kc * 32 + g * 8]);
#pragma unroll
        for (int tt = 0; tt < 8; ++tt) {
            short8 b = *(const short8*)(&Bs[(tt * 16 + m) * LPITCH + kc * 32 + g * 8]);
            acc2[tt] = __builtin_amdgcn_mfma_f32_16x16x32_bf16(a, b, acc2[tt], 0, 0, 0);
        }
    }

    float* csum = (float*)As;
    float* csq = csum + DIM;
    __syncthreads();
    if (t < DIM) { csum[t] = 0.f; csq[t] = 0.f; }
    __syncthreads();
#pragma unroll
    for (int tt = 0; tt < 8; ++tt) {
        int col = tt * 16 + m;
        float bv = bias2[col];
        float s = 0.f, q = 0.f;
#pragma unroll
        for (int j = 0; j < 4; ++j) {
            int row = row0 + wv * 16 + g * 4 + j;
            float v = acc2[tt][j] + bv;
            outb[(size_t)row * DIM + col] = f2bf(v);
            if (row < N_NODES) { s += v; q += v * v; }
        }
        atomicAdd(&csum[col], s);
        atomicAdd(&csq[col], q);
    }
    __syncthreads();
    gpart[(size_t)blockIdx.x * 256 + t] = (t < DIM) ? csum[t] : csq[t - DIM];
}

// ---------------------------------------------------------------------------
// Reduce GBLK x 256 partials -> gstats[256].
// ---------------------------------------------------------------------------
__global__ __launch_bounds__(256) void reduce_stats(
    const float* __restrict__ gpart, float* __restrict__ gstats) {
    int t = threadIdx.x;
    int chunk = (GBLK + 31) / 32;            // 49
    int r0 = blockIdx.x * chunk;
    int r1 = r0 + chunk < GBLK ? r0 + chunk : GBLK;
    float s = 0.f;
    for (int r = r0; r < r1; ++r) s += gpart[(size_t)r * 256 + t];
    atomicAdd(&gstats[t], s);
}

// ---------------------------------------------------------------------------
// BN finalize (redundant per block) + apply.
// ---------------------------------------------------------------------------
__global__ __launch_bounds__(256) void bn_apply(
    const unsigned short* __restrict__ H2, const float* __restrict__ gstats,
    const float* __restrict__ gamma, const float* __restrict__ beta,
    float* __restrict__ out) {
    __shared__ float sc_s[DIM], sh_s[DIM];
    int t = threadIdx.x;
    if (t < DIM) {
        float mean = gstats[t] * (1.0f / N_NODES);
        float m2 = gstats[DIM + t] * (1.0f / N_NODES);
        float var = m2 - mean * mean;
        float inv = rsqrtf(var + EPS_BN);
        float sc = gamma[t] * inv;
        sc_s[t] = sc;
        sh_s[t] = beta[t] - mean * sc;
    }
    __syncthreads();
    int i = blockIdx.x * 256 + t;
    int j4 = (i & 31) * 4;
    ushort4 hv = ((const ushort4*)H2)[i];
    float4 o;
    o.x = bf2f(hv.x) * sc_s[j4 + 0] + sh_s[j4 + 0];
    o.y = bf2f(hv.y) * sc_s[j4 + 1] + sh_s[j4 + 1];
    o.z = bf2f(hv.z) * sc_s[j4 + 2] + sh_s[j4 + 2];
    o.w = bf2f(hv.w) * sc_s[j4 + 3] + sh_s[j4 + 3];
    ((float4*)out)[i] = o;
}

// ---------------------------------------------------------------------------
extern "C" void kernel_launch(void* const* d_in, const int* in_sizes, int n_in,
                              void* d_out, int out_size, void* d_ws,
                              size_t ws_size, hipStream_t stream) {
    (void)in_sizes; (void)n_in; (void)out_size; (void)ws_size;
    const float* x     = (const float*)d_in[0];
    const void*  eidx  = d_in[1];
    const float* W1    = (const float*)d_in[2];
    const float* b1    = (const float*)d_in[3];
    const float* W2    = (const float*)d_in[4];
    const float* b2    = (const float*)d_in[5];
    const float* gamma = (const float*)d_in[6];
    const float* beta  = (const float*)d_in[7];
    float* out = (float*)d_out;

    char* p = (char*)d_ws;
    auto alloc = [&](size_t bytes) {
        char* r = p;
        p += (bytes + 255) & ~(size_t)255;
        return r;
    };
    unsigned short* Hbf  = (unsigned short*)alloc((size_t)M_PAD * DIM * 2); // 25.6MB
    unsigned short* h2bf = (unsigned short*)alloc((size_t)M_PAD * DIM * 2); // 25.6MB
    // slots (8.4MB, packed 4B) alias h2bf: dead before mlp writes h2
    unsigned* slots = (unsigned*)h2bf;
    unsigned short* xb = (unsigned short*)alloc((size_t)N_NODES * DIM * 2);  // 25.6MB
    int*   cols   = (int*)alloc((size_t)(N_EDGES + 64) * 4);                 // 6.4MB
    float* gpart  = (float*)alloc((size_t)GBLK * 256 * 4);                   // 1.6MB
    int*   rowst  = (int*)alloc((size_t)(N_NODES + 1) * 4);
    int*   bcur   = (int*)alloc(NB * 4);
    unsigned short* W1t = (unsigned short*)alloc(DIM * DIM * 2);
    unsigned short* W2t = (unsigned short*)alloc(DIM * DIM * 2);
    float* gstats = (float*)alloc(2 * DIM * 4);

    convert_w<<<3, 256, 0, stream>>>(W1, W2, W1t, W2t, bcur, gstats);
    bin_scatter_x<<<NBLK, 1024, 0, stream>>>(eidx, bcur, slots, x, xb);
    build_csr<<<NB, 1024, 0, stream>>>(slots, bcur, rowst, cols);

    agg_kernel<<<N_NODES / 4, 256, 0, stream>>>(xb, rowst, cols, Hbf);

    mlp_fused<<<GBLK, 256, 0, stream>>>(Hbf, W1t, W2t, b1, b2, h2bf, gpart);
    reduce_stats<<<32, 256, 0, stream>>>(gpart, gstats);
    bn_apply<<<(N_NODES * DIM / 4) / 256, 256, 0, stream>>>(h2bf, gstats,
                                                            gamma, beta, out);
}

// Round 8
// 285.042 us; speedup vs baseline: 1.6318x; 1.0180x over previous
//
#include <hip/hip_runtime.h>

#define N_NODES 100000
#define N_EDGES 1600000
#define DIM     128
#define EPS_BN  1e-5f
#define NB      512      // buckets
#define NPB     196      // nodes per bucket (512*196 >= 100000)
#define NBLK    256      // bin_scatter blocks
#define EPB     6250     // edges per bin_scatter block (256*6250 == N_EDGES)
#define CAP     4096     // slot capacity per bucket (mean 3125, sigma~56, +17s)
#define M_TILE  64
#define M_PAD   100032   // 1563 * 64
#define GBLK    1563     // M_PAD / M_TILE
#define LPITCH  136      // LDS pitch in bf16 units (272B = 17*16B, b128-aligned)

typedef __attribute__((ext_vector_type(8))) short short8;
typedef __attribute__((ext_vector_type(4))) float floatx4;

__device__ __forceinline__ unsigned short f2bf(float f) {   // RNE bf16 bits
    unsigned u = __float_as_uint(f);
    return (unsigned short)((u + 0x7FFF + ((u >> 16) & 1)) >> 16);
}
__device__ __forceinline__ float bf2f(unsigned short b) {
    return __uint_as_float((unsigned)b << 16);
}

// int64 layout => odd int32 words all zero. Wave-uniform result.
__device__ __forceinline__ int detect64(const void* eidx) {
    int v = ((const int*)eidx)[2 * (threadIdx.x & 63) + 1];
    unsigned long long b = __ballot(v != 0);
    return (b == 0ULL) ? 1 : 0;
}
__device__ __forceinline__ int load_row(const void* eidx, int is64, int e) {
    if (is64) return (int)((const long long*)eidx)[e];
    return ((const int*)eidx)[e];
}
__device__ __forceinline__ int load_col(const void* eidx, int is64, int e) {
    if (is64) return (int)((const long long*)eidx)[N_EDGES + e];
    return ((const int*)eidx)[N_EDGES + e];
}

// ---------------------------------------------------------------------------
// convert_w + workspace init: blocks 0/1 transpose W1/W2 to bf16 [n][k];
// block 2 zeroes bcur + gstats.
// ---------------------------------------------------------------------------
__global__ void convert_w(const float* __restrict__ W1,
                          const float* __restrict__ W2,
                          unsigned short* __restrict__ W1t,
                          unsigned short* __restrict__ W2t,
                          int* __restrict__ bcur, float* __restrict__ gstats) {
    if (blockIdx.x == 2) {
        int t = threadIdx.x;
        bcur[t] = 0;
        bcur[256 + t] = 0;
        if (t < 2 * DIM) gstats[t] = 0.f;
        return;
    }
    const float* W = blockIdx.x ? W2 : W1;
    unsigned short* Wt = blockIdx.x ? W2t : W1t;
    for (int i = threadIdx.x; i < DIM * DIM; i += 256) {
        int k = i >> 7, n = i & 127;
        Wt[n * DIM + k] = f2bf(W[i]);
    }
}

// ---------------------------------------------------------------------------
// bin_scatter_x: 256 blocks x 1024 threads (round-6 proven). hist -> LDS
// scan -> per-bucket global range claim -> LDS bucket-sorted staging
// (packed 4B: row_local<<24 | col) -> LINEAR copy out. Then grid-stride
// xconv. LDS: 3*2KB + 25KB stage + 25KB gaddr = 56KB.
// Overflow-hardened: writes past a full bucket (CAP) are dropped (never
// statistically reachable; protects against OOB on adversarial input).
// ---------------------------------------------------------------------------
__global__ __launch_bounds__(1024) void bin_scatter_x(
    const void* eidx, int* bcur, unsigned* __restrict__ slots,
    const float* __restrict__ x, unsigned short* __restrict__ xb) {
    __shared__ int lh[NB];
    __shared__ int lbase[NB];
    __shared__ int loff[NB];
    __shared__ unsigned stage[EPB];
    __shared__ int gaddr[EPB];
    int t = threadIdx.x;
    int is64 = detect64(eidx);
    if (t < NB) lh[t] = 0;
    __syncthreads();
    int base = blockIdx.x * EPB;
    for (int i = t; i < EPB; i += 1024) {
        int r = load_row(eidx, is64, base + i);
        atomicAdd(&lh[r / NPB], 1);
    }
    __syncthreads();
    // inclusive scan of lh[0..511] into loff (threads 0..511, 1 elem each)
    if (t < NB) loff[t] = lh[t];
    __syncthreads();
    for (int off = 1; off < NB; off <<= 1) {
        int a = (t >= off && t < NB) ? loff[t - off] : 0;
        __syncthreads();
        if (t < NB) loff[t] += a;
        __syncthreads();
    }
    // claim global ranges, make loff exclusive, reset lh for scatter cursors
    if (t < NB) {
        int c = lh[t];
        lbase[t] = c ? atomicAdd(&bcur[t], c) : 0;
        loff[t] -= c;
        lh[t] = 0;
    }
    __syncthreads();
    for (int i = t; i < EPB; i += 1024) {
        int r = load_row(eidx, is64, base + i);
        int c = load_col(eidx, is64, base + i);
        int b = r / NPB;
        int pos = atomicAdd(&lh[b], 1);
        int idx = loff[b] + pos;
        int ga = lbase[b] + pos;
        if (ga >= CAP) ga = CAP - 1;          // clamp (never taken in practice)
        stage[idx] = ((unsigned)(r - b * NPB) << 24) | (unsigned)c;
        gaddr[idx] = b * CAP + ga;
    }
    __syncthreads();
    for (int i = t; i < EPB; i += 1024)       // linear: runs coalesce to lines
        slots[gaddr[i]] = stage[i];
    // ---- fused xconv: grid-stride f32 -> bf16 (no barrier needed) ----
    for (int i = blockIdx.x * 1024 + t; i < N_NODES * DIM / 4; i += NBLK * 1024) {
        float4 v = ((const float4*)x)[i];
        ushort4 o;
        o.x = f2bf(v.x); o.y = f2bf(v.y); o.z = f2bf(v.z); o.w = f2bf(v.w);
        ((ushort4*)xb)[i] = o;
    }
}

// ---------------------------------------------------------------------------
// csr_agg: replaces build_csr + agg_kernel. One block (1024 threads) per
// bucket: within-bucket hist/scan/scatter into LDS colbuf (no global
// cols/rowst round-trip, no 512-wide global scan), then the proven 16-deep
// pipelined gather runs straight off the LDS lists. 2 blocks/CU = 32
// waves/CU: the sort's VALU/LDS work of one block hides under the other's
// fabric-BW-bound gather.  LDS ~= 20KB. VGPR capped via launch_bounds.
// ---------------------------------------------------------------------------
__global__ __launch_bounds__(1024, 8) void csr_agg(
    const unsigned short* __restrict__ xb,
    const unsigned* __restrict__ slots,
    const int* __restrict__ bcnt,
    unsigned short* __restrict__ Hbf) {
    __shared__ int hist[256];
    __shared__ int incl[256];                 // inclusive scan (row ranges)
    __shared__ int cur[256];                  // scatter cursors
    __shared__ int colbuf[CAP];
    int t = threadIdx.x;
    int b = blockIdx.x;
    int cnt = bcnt[b];
    if (cnt > CAP) cnt = CAP;                 // clamp (never taken in practice)
    if (cnt < 0) cnt = 0;
    int node0 = b * NPB;
    int nn = N_NODES - node0;
    if (nn > NPB) nn = NPB;
    if (nn < 0) nn = 0;
    const unsigned* pairs = slots + (size_t)b * CAP;
    if (t < 256) hist[t] = 0;
    __syncthreads();
    for (int i = t; i < cnt; i += 1024)
        atomicAdd(&hist[(int)(pairs[i] >> 24)], 1);
    __syncthreads();
    int v = (t < 256) ? hist[t] : 0;
    if (t < 256) incl[t] = v;
    __syncthreads();
    for (int off = 1; off < 256; off <<= 1) {
        int a = (t >= off && t < 256) ? incl[t - off] : 0;
        __syncthreads();
        if (t < 256) incl[t] += a;
        __syncthreads();
    }
    if (t < 256) cur[t] = incl[t] - v;        // exclusive start
    __syncthreads();
    for (int i = t; i < cnt; i += 1024) {
        unsigned pr = pairs[i];
        int pos = atomicAdd(&cur[pr >> 24], 1);
        if (pos < CAP) colbuf[pos] = (int)(pr & 0xFFFFFFu);
    }
    __syncthreads();

    // ---- aggregation straight off LDS lists (round-0 proven pipeline) ----
    const unsigned* xbw = (const unsigned*)xb;    // 64 words per row
    int lane = t & 63, wv = t >> 6;
    for (int nl = wv; nl < nn; nl += 16) {
        int node = node0 + nl;
        unsigned selfw = xbw[(size_t)node * 64 + lane];
        float2 acc;
        acc.x = __uint_as_float(selfw << 16);
        acc.y = __uint_as_float(selfw & 0xffff0000u);
        int e = incl[nl];
        int s = nl ? incl[nl - 1] : 0;
        s = __builtin_amdgcn_readfirstlane(s);
        e = __builtin_amdgcn_readfirstlane(e);
        int d = e - s;
        if (d <= 16) {
            unsigned pw[16];
#pragma unroll
            for (int u = 0; u < 16; ++u) {
                int idx = s + u;
                int ci = (idx < e) ? idx : s;          // clamp: dup row, L1 hit
                pw[u] = xbw[(size_t)colbuf[ci] * 64 + lane];
            }
#pragma unroll
            for (int u = 0; u < 16; ++u) {
                unsigned w = (u < d) ? pw[u] : 0u;     // masked accumulate
                acc.x += __uint_as_float(w << 16);
                acc.y += __uint_as_float(w & 0xffff0000u);
            }
        } else {
            int j = s;
            for (; j + 16 <= e; j += 16) {
                unsigned pw[16];
#pragma unroll
                for (int u = 0; u < 16; ++u)
                    pw[u] = xbw[(size_t)colbuf[j + u] * 64 + lane];
#pragma unroll
                for (int u = 0; u < 16; ++u) {
                    acc.x += __uint_as_float(pw[u] << 16);
                    acc.y += __uint_as_float(pw[u] & 0xffff0000u);
                }
            }
            if (j < e) {
                unsigned pw[16];
                int dd = e - j;
#pragma unroll
                for (int u = 0; u < 16; ++u) {
                    int idx = j + u;
                    int ci = (idx < e) ? idx : s;
                    pw[u] = xbw[(size_t)colbuf[ci] * 64 + lane];
                }
#pragma unroll
                for (int u = 0; u < 16; ++u) {
                    unsigned w = (u < dd) ? pw[u] : 0u;
                    acc.x += __uint_as_float(w << 16);
                    acc.y += __uint_as_float(w & 0xffff0000u);
                }
            }
        }
        unsigned pack = (unsigned)f2bf(acc.x) | ((unsigned)f2bf(acc.y) << 16);
        ((unsigned*)Hbf)[(size_t)node * 64 + lane] = pack;
    }
}

// ---------------------------------------------------------------------------
// Fused MLP (round-0 proven): h2 = (relu(A@W1+b1))@W2 + b2 per 64-row tile;
// BN stats leave as per-block partials. 52KB LDS -> 3 blocks/CU.
// ---------------------------------------------------------------------------
__global__ __launch_bounds__(256) void mlp_fused(
    const unsigned short* __restrict__ A,    // M_PAD x 128 bf16
    const unsigned short* __restrict__ B1t,  // W1^T bf16 [n][k]
    const unsigned short* __restrict__ B2t,  // W2^T bf16 [n][k]
    const float* __restrict__ bias1, const float* __restrict__ bias2,
    unsigned short* __restrict__ outb,       // M_PAD x 128 bf16
    float* __restrict__ gpart) {             // GBLK x 256 partials
    __shared__ unsigned short As[M_TILE * LPITCH];   // 17408 B
    __shared__ unsigned short Bs[DIM * LPITCH];      // 34816 B
    int t = threadIdx.x;
    int row0 = blockIdx.x * M_TILE;
    int lane = t & 63, wv = t >> 6;
    int m = lane & 15, g = lane >> 4;

#pragma unroll
    for (int i = 0; i < 4; ++i) {
        int ch = t + 256 * i;
        int r = ch >> 4, cc = ch & 15;
        *(uint4*)(&As[r * LPITCH + cc * 8]) =
            *(const uint4*)(&A[(size_t)(row0 + r) * DIM + cc * 8]);
    }
#pragma unroll
    for (int i = 0; i < 8; ++i) {
        int ch = t + 256 * i;
        int n = ch >> 4, cc = ch & 15;
        *(uint4*)(&Bs[n * LPITCH + cc * 8]) =
            *(const uint4*)(&B1t[n * DIM + cc * 8]);
    }
    __syncthreads();

    floatx4 acc1[8] = {};
#pragma unroll
    for (int kc = 0; kc < 4; ++kc) {
        short8 a = *(const short8*)(&As[(wv * 16 + m) * LPITCH + kc * 32 + g * 8]);
#pragma unroll
        for (int tt = 0; tt < 8; ++tt) {
            short8 b = *(const short8*)(&Bs[(tt * 16 + m) * LPITCH + kc * 32 + g * 8]);
            acc1[tt] = __builtin_amdgcn_mfma_f32_16x16x32_bf16(a, b, acc1[tt], 0, 0, 0);
        }
    }
    __syncthreads();

    uint4 wbuf[8];
#pragma unroll
    for (int i = 0; i < 8; ++i) {
        int ch = t + 256 * i;
        int n = ch >> 4, cc = ch & 15;
        wbuf[i] = *(const uint4*)(&B2t[n * DIM + cc * 8]);
    }
#pragma unroll
    for (int tt = 0; tt < 8; ++tt) {
        int col = tt * 16 + m;
        float bv = bias1[col];
#pragma unroll
        for (int j = 0; j < 4; ++j) {
            int rl = wv * 16 + g * 4 + j;
            As[rl * LPITCH + col] = f2bf(fmaxf(acc1[tt][j] + bv, 0.f));
        }
    }
#pragma unroll
    for (int i = 0; i < 8; ++i) {
        int ch = t + 256 * i;
        int n = ch >> 4, cc = ch & 15;
        *(uint4*)(&Bs[n * LPITCH + cc * 8]) = wbuf[i];
    }
    __syncthreads();

    floatx4 acc2[8] = {};
#pragma unroll
    for (int kc = 0; kc < 4; ++kc) {
        short8 a = *(const short8*)(&As[(wv * 16 + m) * LPITCH + kc * 32 + g * 8]);
#pragma unroll
        for (int tt = 0; tt < 8; ++tt) {
            short8 b = *(const short8*)(&Bs[(tt * 16 + m) * LPITCH + kc * 32 + g * 8]);
            acc2[tt] = __builtin_amdgcn_mfma_f32_16x16x32_bf16(a, b, acc2[tt], 0, 0, 0);
        }
    }

    float* csum = (float*)As;
    float* csq = csum + DIM;
    __syncthreads();
    if (t < DIM) { csum[t] = 0.f; csq[t] = 0.f; }
    __syncthreads();
#pragma unroll
    for (int tt = 0; tt < 8; ++tt) {
        int col = tt * 16 + m;
        float bv = bias2[col];
        float s = 0.f, q = 0.f;
#pragma unroll
        for (int j = 0; j < 4; ++j) {
            int row = row0 + wv * 16 + g * 4 + j;
            float v = acc2[tt][j] + bv;
            outb[(size_t)row * DIM + col] = f2bf(v);
            if (row < N_NODES) { s += v; q += v * v; }
        }
        atomicAdd(&csum[col], s);
        atomicAdd(&csq[col], q);
    }
    __syncthreads();
    gpart[(size_t)blockIdx.x * 256 + t] = (t < DIM) ? csum[t] : csq[t - DIM];
}

// ---------------------------------------------------------------------------
// Reduce GBLK x 256 partials -> gstats[256].
// ---------------------------------------------------------------------------
__global__ __launch_bounds__(256) void reduce_stats(
    const float* __restrict__ gpart, float* __restrict__ gstats) {
    int t = threadIdx.x;
    int chunk = (GBLK + 31) / 32;            // 49
    int r0 = blockIdx.x * chunk;
    int r1 = r0 + chunk < GBLK ? r0 + chunk : GBLK;
    float s = 0.f;
    for (int r = r0; r < r1; ++r) s += gpart[(size_t)r * 256 + t];
    atomicAdd(&gstats[t], s);
}

// ---------------------------------------------------------------------------
// BN finalize (redundant per block) + apply.
// ---------------------------------------------------------------------------
__global__ __launch_bounds__(256) void bn_apply(
    const unsigned short* __restrict__ H2, const float* __restrict__ gstats,
    const float* __restrict__ gamma, const float* __restrict__ beta,
    float* __restrict__ out) {
    __shared__ float sc_s[DIM], sh_s[DIM];
    int t = threadIdx.x;
    if (t < DIM) {
        float mean = gstats[t] * (1.0f / N_NODES);
        float m2 = gstats[DIM + t] * (1.0f / N_NODES);
        float var = m2 - mean * mean;
        float inv = rsqrtf(var + EPS_BN);
        float sc = gamma[t] * inv;
        sc_s[t] = sc;
        sh_s[t] = beta[t] - mean * sc;
    }
    __syncthreads();
    int i = blockIdx.x * 256 + t;
    int j4 = (i & 31) * 4;
    ushort4 hv = ((const ushort4*)H2)[i];
    float4 o;
    o.x = bf2f(hv.x) * sc_s[j4 + 0] + sh_s[j4 + 0];
    o.y = bf2f(hv.y) * sc_s[j4 + 1] + sh_s[j4 + 1];
    o.z = bf2f(hv.z) * sc_s[j4 + 2] + sh_s[j4 + 2];
    o.w = bf2f(hv.w) * sc_s[j4 + 3] + sh_s[j4 + 3];
    ((float4*)out)[i] = o;
}

// ---------------------------------------------------------------------------
extern "C" void kernel_launch(void* const* d_in, const int* in_sizes, int n_in,
                              void* d_out, int out_size, void* d_ws,
                              size_t ws_size, hipStream_t stream) {
    (void)in_sizes; (void)n_in; (void)out_size; (void)ws_size;
    const float* x     = (const float*)d_in[0];
    const void*  eidx  = d_in[1];
    const float* W1    = (const float*)d_in[2];
    const float* b1    = (const float*)d_in[3];
    const float* W2    = (const float*)d_in[4];
    const float* b2    = (const float*)d_in[5];
    const float* gamma = (const float*)d_in[6];
    const float* beta  = (const float*)d_in[7];
    float* out = (float*)d_out;

    char* p = (char*)d_ws;
    auto alloc = [&](size_t bytes) {
        char* r = p;
        p += (bytes + 255) & ~(size_t)255;
        return r;
    };
    unsigned short* Hbf  = (unsigned short*)alloc((size_t)M_PAD * DIM * 2); // 25.6MB
    unsigned short* h2bf = (unsigned short*)alloc((size_t)M_PAD * DIM * 2); // 25.6MB
    // slots (8.4MB, packed 4B) alias h2bf: dead before mlp writes h2
    unsigned* slots = (unsigned*)h2bf;
    unsigned short* xb = (unsigned short*)alloc((size_t)N_NODES * DIM * 2);  // 25.6MB
    float* gpart  = (float*)alloc((size_t)GBLK * 256 * 4);                   // 1.6MB
    int*   bcur   = (int*)alloc(NB * 4);
    unsigned short* W1t = (unsigned short*)alloc(DIM * DIM * 2);
    unsigned short* W2t = (unsigned short*)alloc(DIM * DIM * 2);
    float* gstats = (float*)alloc(2 * DIM * 4);

    convert_w<<<3, 256, 0, stream>>>(W1, W2, W1t, W2t, bcur, gstats);
    bin_scatter_x<<<NBLK, 1024, 0, stream>>>(eidx, bcur, slots, x, xb);
    csr_agg<<<NB, 1024, 0, stream>>>(xb, slots, bcur, Hbf);

    mlp_fused<<<GBLK, 256, 0, stream>>>(Hbf, W1t, W2t, b1, b2, h2bf, gpart);
    reduce_stats<<<32, 256, 0, stream>>>(gpart, gstats);
    bn_apply<<<(N_NODES * DIM / 4) / 256, 256, 0, stream>>>(h2bf, gstats,
                                                            gamma, beta, out);
}

// Round 9
// 264.071 us; speedup vs baseline: 1.7614x; 1.0794x over previous
//
#include <hip/hip_runtime.h>

#define N_NODES 100000
#define N_EDGES 1600000
#define DIM     128
#define EPS_BN  1e-5f
#define NB      1024     // buckets
#define NPB     98       // nodes per bucket (1024*98 = 100352 >= 100000)
#define NBLK    256      // bin_scatter blocks
#define EPB     6250     // edges per bin_scatter block (256*6250 == N_EDGES)
#define CAP     2048     // slot capacity per bucket (mean 1562.5, sigma~40)
#define PADR    112      // As rows (7 tiles of 16 >= NPB)
#define NT      7        // MFMA row-tiles per bucket
#define LPITCH  136      // LDS pitch in bf16 units (272B = 17*16B, b128-aligned)

typedef __attribute__((ext_vector_type(8))) short short8;
typedef __attribute__((ext_vector_type(4))) float floatx4;

__device__ __forceinline__ unsigned short f2bf(float f) {   // RNE bf16 bits
    unsigned u = __float_as_uint(f);
    return (unsigned short)((u + 0x7FFF + ((u >> 16) & 1)) >> 16);
}
__device__ __forceinline__ float bf2f(unsigned short b) {
    return __uint_as_float((unsigned)b << 16);
}

// int64 layout => odd int32 words all zero. Wave-uniform result.
__device__ __forceinline__ int detect64(const void* eidx) {
    int v = ((const int*)eidx)[2 * (threadIdx.x & 63) + 1];
    unsigned long long b = __ballot(v != 0);
    return (b == 0ULL) ? 1 : 0;
}
__device__ __forceinline__ int load_row(const void* eidx, int is64, int e) {
    if (is64) return (int)((const long long*)eidx)[e];
    return ((const int*)eidx)[e];
}
__device__ __forceinline__ int load_col(const void* eidx, int is64, int e) {
    if (is64) return (int)((const long long*)eidx)[N_EDGES + e];
    return ((const int*)eidx)[N_EDGES + e];
}

// ---------------------------------------------------------------------------
// bin_scatter_xw: 256 blocks x 1024 threads. hist -> LDS scan (1024 buckets)
// -> per-bucket global range claim -> LDS bucket-sorted staging (packed 4B:
// row_local<<24 | col) -> LINEAR copy out (runs ~6 slots; cross-block ranges
// are contiguous so L2 merges lines; slots=8.4MB stays L2-resident). Blocks
// 0/1 also transpose W1/W2 to bf16 [n][k]. Then grid-stride xconv.
// LDS: 3*4KB tables + 25KB stage + 25KB gaddr = 62KB; 2 blocks/CU (threads).
// ---------------------------------------------------------------------------
__global__ __launch_bounds__(1024) void bin_scatter_xw(
    const void* eidx, int* bcur, unsigned* __restrict__ slots,
    const float* __restrict__ x, unsigned short* __restrict__ xb,
    const float* __restrict__ W1, const float* __restrict__ W2,
    unsigned short* __restrict__ W1t, unsigned short* __restrict__ W2t) {
    __shared__ int lh[NB];
    __shared__ int lbase[NB];
    __shared__ int loff[NB];
    __shared__ unsigned stage[EPB];
    __shared__ int gaddr[EPB];
    int t = threadIdx.x;
    int is64 = detect64(eidx);
    lh[t] = 0;
    __syncthreads();
    int base = blockIdx.x * EPB;
    for (int i = t; i < EPB; i += 1024) {
        int r = load_row(eidx, is64, base + i);
        atomicAdd(&lh[r / NPB], 1);
    }
    __syncthreads();
    // inclusive scan of lh[0..1023] into loff (1 elem/thread)
    loff[t] = lh[t];
    __syncthreads();
    for (int off = 1; off < NB; off <<= 1) {
        int a = (t >= off) ? loff[t - off] : 0;
        __syncthreads();
        loff[t] += a;
        __syncthreads();
    }
    // claim global ranges, make loff exclusive, reset lh for scatter cursors
    {
        int c = lh[t];
        lbase[t] = c ? atomicAdd(&bcur[t], c) : 0;
        loff[t] -= c;
        lh[t] = 0;
    }
    __syncthreads();
    for (int i = t; i < EPB; i += 1024) {
        int r = load_row(eidx, is64, base + i);
        int c = load_col(eidx, is64, base + i);
        int b = r / NPB;
        int pos = atomicAdd(&lh[b], 1);
        int idx = loff[b] + pos;
        int ga = lbase[b] + pos;
        if (ga >= CAP) ga = CAP - 1;          // clamp (never taken in practice)
        stage[idx] = ((unsigned)(r - b * NPB) << 24) | (unsigned)c;
        gaddr[idx] = b * CAP + ga;
    }
    __syncthreads();
    for (int i = t; i < EPB; i += 1024)       // linear: runs coalesce to lines
        slots[gaddr[i]] = stage[i];
    // ---- W transpose (blocks 0/1) ----
    if (blockIdx.x < 2) {
        const float* W = blockIdx.x ? W2 : W1;
        unsigned short* Wt = blockIdx.x ? W2t : W1t;
        for (int i = t; i < DIM * DIM; i += 1024) {
            int k = i >> 7, n = i & 127;
            Wt[n * DIM + k] = f2bf(W[i]);
        }
    }
    // ---- fused xconv: grid-stride f32 -> bf16 ----
    for (int i = blockIdx.x * 1024 + t; i < N_NODES * DIM / 4; i += NBLK * 1024) {
        float4 v = ((const float4*)x)[i];
        ushort4 o;
        o.x = f2bf(v.x); o.y = f2bf(v.y); o.z = f2bf(v.z); o.w = f2bf(v.w);
        ((ushort4*)xb)[i] = o;
    }
}

// ---------------------------------------------------------------------------
// csr_agg_mlp: one block (1024 thr) per bucket. Phases: (1) in-LDS sort of
// the bucket's edges (hist/scan/scatter, round-8 proven); (2) 16-deep
// pipelined gather aggregates each node's row straight into the As LDS tile;
// (3) inline MLP: 7 of 16 waves run the round-0 mlp_fused MFMA sequence
// (W1 staged at entry, W2 swapped after GEMM1), h2 + BN partials written
// directly. Kills the Hbf round-trip (51MB), the mlp_fused launch, and its
// A/W staging. LDS = 1.5K tables + 8K colbuf + 30.5K As + 34K Bs = 73.3KB:
// still 2 blocks/CU (thread-limited, round-8 evidence). VGPR forced <=64 by
// launch_bounds so 32 waves/CU hold.
// ---------------------------------------------------------------------------
__global__ __launch_bounds__(1024, 8) void csr_agg_mlp(
    const unsigned short* __restrict__ xb,
    const unsigned* __restrict__ slots,
    const int* __restrict__ bcnt,
    const unsigned short* __restrict__ B1t,
    const unsigned short* __restrict__ B2t,
    const float* __restrict__ bias1, const float* __restrict__ bias2,
    unsigned short* __restrict__ h2,         // N_NODES x 128 bf16
    float* __restrict__ gpart) {             // NB x 256 partials
    __shared__ int hist[128];
    __shared__ int incl[128];                 // inclusive scan (row ranges)
    __shared__ int cur[128];                  // scatter cursors
    __shared__ int colbuf[CAP];               // 8KB; reused as csum/csq later
    __shared__ unsigned short As[PADR * LPITCH];   // 30464 B
    __shared__ unsigned short Bs[DIM * LPITCH];    // 34816 B
    int t = threadIdx.x;
    int b = blockIdx.x;
    int lane = t & 63, wv = t >> 6;
    int m = lane & 15, g = lane >> 4;
    int cnt = bcnt[b];
    if (cnt > CAP) cnt = CAP;                 // clamp (never taken in practice)
    if (cnt < 0) cnt = 0;
    int node0 = b * NPB;
    int nn = N_NODES - node0;
    if (nn > NPB) nn = NPB;
    if (nn < 0) nn = 0;
    const unsigned* pairs = slots + (size_t)b * CAP;

    // stage W1 -> Bs (2 x uint4 per thread)
#pragma unroll
    for (int i = 0; i < 2; ++i) {
        int ch = t + 1024 * i;
        int n = ch >> 4, cc = ch & 15;
        *(uint4*)(&Bs[n * LPITCH + cc * 8]) =
            *(const uint4*)(&B1t[n * DIM + cc * 8]);
    }
    if (t < 128) hist[t] = 0;
    __syncthreads();
    for (int i = t; i < cnt; i += 1024)
        atomicAdd(&hist[(int)(pairs[i] >> 24)], 1);
    __syncthreads();
    int v = (t < 128) ? hist[t] : 0;
    if (t < 128) incl[t] = v;
    __syncthreads();
    for (int off = 1; off < 128; off <<= 1) {
        int a = (t >= off && t < 128) ? incl[t - off] : 0;
        __syncthreads();
        if (t < 128) incl[t] += a;
        __syncthreads();
    }
    if (t < 128) cur[t] = incl[t] - v;        // exclusive start
    __syncthreads();
    for (int i = t; i < cnt; i += 1024) {
        unsigned pr = pairs[i];
        int pos = atomicAdd(&cur[pr >> 24], 1);
        if (pos < CAP) colbuf[pos] = (int)(pr & 0xFFFFFFu);
    }
    __syncthreads();

    // ---- aggregation straight off LDS lists into As (16 waves, 7 rows ea) ----
    const unsigned* xbw = (const unsigned*)xb;    // 64 words per row
    for (int nl = wv; nl < PADR; nl += 16) {
        unsigned pack = 0u;
        if (nl < nn) {
            int node = node0 + nl;
            unsigned selfw = xbw[(size_t)node * 64 + lane];
            float ax = __uint_as_float(selfw << 16);
            float ay = __uint_as_float(selfw & 0xffff0000u);
            int e = incl[nl];
            int s = nl ? incl[nl - 1] : 0;
            s = __builtin_amdgcn_readfirstlane(s);
            e = __builtin_amdgcn_readfirstlane(e);
            int d = e - s;
            if (d <= 16) {
                unsigned pw[16];
#pragma unroll
                for (int u = 0; u < 16; ++u) {
                    int idx = s + u;
                    int ci = (idx < e) ? idx : s;      // clamp: dup row, L1 hit
                    pw[u] = xbw[(size_t)colbuf[ci] * 64 + lane];
                }
#pragma unroll
                for (int u = 0; u < 16; ++u) {
                    unsigned w = (u < d) ? pw[u] : 0u; // masked accumulate
                    ax += __uint_as_float(w << 16);
                    ay += __uint_as_float(w & 0xffff0000u);
                }
            } else {
                int j = s;
                for (; j + 16 <= e; j += 16) {
                    unsigned pw[16];
#pragma unroll
                    for (int u = 0; u < 16; ++u)
                        pw[u] = xbw[(size_t)colbuf[j + u] * 64 + lane];
#pragma unroll
                    for (int u = 0; u < 16; ++u) {
                        ax += __uint_as_float(pw[u] << 16);
                        ay += __uint_as_float(pw[u] & 0xffff0000u);
                    }
                }
                if (j < e) {
                    unsigned pw[16];
                    int dd = e - j;
#pragma unroll
                    for (int u = 0; u < 16; ++u) {
                        int idx = j + u;
                        int ci = (idx < e) ? idx : s;
                        pw[u] = xbw[(size_t)colbuf[ci] * 64 + lane];
                    }
#pragma unroll
                    for (int u = 0; u < 16; ++u) {
                        unsigned w = (u < dd) ? pw[u] : 0u;
                        ax += __uint_as_float(w << 16);
                        ay += __uint_as_float(w & 0xffff0000u);
                    }
                }
            }
            pack = (unsigned)f2bf(ax) | ((unsigned)f2bf(ay) << 16);
        }
        *(unsigned*)(&As[nl * LPITCH + lane * 2]) = pack;   // pad rows: zero
    }
    __syncthreads();

    // ---- GEMM1: acc1 = A@W1 (waves 0..6, one 16-row tile each) ----
    floatx4 acc1[8];
    if (wv < NT) {
#pragma unroll
        for (int tt = 0; tt < 8; ++tt) acc1[tt] = (floatx4){0.f, 0.f, 0.f, 0.f};
#pragma unroll
        for (int kc = 0; kc < 4; ++kc) {
            short8 a = *(const short8*)(&As[(wv * 16 + m) * LPITCH + kc * 32 + g * 8]);
#pragma unroll
            for (int tt = 0; tt < 8; ++tt) {
                short8 bb = *(const short8*)(&Bs[(tt * 16 + m) * LPITCH + kc * 32 + g * 8]);
                acc1[tt] = __builtin_amdgcn_mfma_f32_16x16x32_bf16(a, bb, acc1[tt], 0, 0, 0);
            }
        }
    }
    __syncthreads();                          // all Bs/As reads done

    // relu -> As (wave-local rows); stage W2 -> Bs (all threads); zero stats
    if (wv < NT) {
#pragma unroll
        for (int tt = 0; tt < 8; ++tt) {
            int col = tt * 16 + m;
            float bv = bias1[col];
#pragma unroll
            for (int j = 0; j < 4; ++j) {
                int rl = wv * 16 + g * 4 + j;
                As[rl * LPITCH + col] = f2bf(fmaxf(acc1[tt][j] + bv, 0.f));
            }
        }
    }
#pragma unroll
    for (int i = 0; i < 2; ++i) {
        int ch = t + 1024 * i;
        int n = ch >> 4, cc = ch & 15;
        *(uint4*)(&Bs[n * LPITCH + cc * 8]) =
            *(const uint4*)(&B2t[n * DIM + cc * 8]);
    }
    float* csum = (float*)colbuf;             // colbuf dead after agg phase
    if (t < 256) csum[t] = 0.f;               // [0..127]=sum, [128..255]=sq
    __syncthreads();

    // ---- GEMM2 in 2 col-groups of 4 tiles (caps acc2 at 16 VGPR) ----
    if (wv < NT) {
#pragma unroll
        for (int hg = 0; hg < 2; ++hg) {
            floatx4 acc2[4];
#pragma unroll
            for (int q = 0; q < 4; ++q) acc2[q] = (floatx4){0.f, 0.f, 0.f, 0.f};
#pragma unroll
            for (int kc = 0; kc < 4; ++kc) {
                short8 a = *(const short8*)(&As[(wv * 16 + m) * LPITCH + kc * 32 + g * 8]);
#pragma unroll
                for (int q = 0; q < 4; ++q) {
                    int tile = hg * 4 + q;
                    short8 bb = *(const short8*)(&Bs[(tile * 16 + m) * LPITCH + kc * 32 + g * 8]);
                    acc2[q] = __builtin_amdgcn_mfma_f32_16x16x32_bf16(a, bb, acc2[q], 0, 0, 0);
                }
            }
#pragma unroll
            for (int q = 0; q < 4; ++q) {
                int col = (hg * 4 + q) * 16 + m;
                float bv = bias2[col];
                float s = 0.f, qq = 0.f;
#pragma unroll
                for (int j = 0; j < 4; ++j) {
                    int rl = wv * 16 + g * 4 + j;
                    if (rl < nn) {
                        float vv = acc2[q][j] + bv;
                        h2[(size_t)(node0 + rl) * DIM + col] = f2bf(vv);
                        s += vv; qq += vv * vv;
                    }
                }
                atomicAdd(&csum[col], s);
                atomicAdd(&csum[DIM + col], qq);
            }
        }
    }
    __syncthreads();
    if (t < 256) gpart[(size_t)b * 256 + t] = csum[t];
}

// ---------------------------------------------------------------------------
// Reduce NB x 256 partials -> gstats[256].
// ---------------------------------------------------------------------------
__global__ __launch_bounds__(256) void reduce_stats(
    const float* __restrict__ gpart, float* __restrict__ gstats) {
    int t = threadIdx.x;
    int chunk = NB / 32;                      // 32
    int r0 = blockIdx.x * chunk;
    float s = 0.f;
    for (int r = r0; r < r0 + chunk; ++r) s += gpart[(size_t)r * 256 + t];
    atomicAdd(&gstats[t], s);
}

// ---------------------------------------------------------------------------
// BN finalize (redundant per block) + apply.
// ---------------------------------------------------------------------------
__global__ __launch_bounds__(256) void bn_apply(
    const unsigned short* __restrict__ H2, const float* __restrict__ gstats,
    const float* __restrict__ gamma, const float* __restrict__ beta,
    float* __restrict__ out) {
    __shared__ float sc_s[DIM], sh_s[DIM];
    int t = threadIdx.x;
    if (t < DIM) {
        float mean = gstats[t] * (1.0f / N_NODES);
        float m2 = gstats[DIM + t] * (1.0f / N_NODES);
        float var = m2 - mean * mean;
        float inv = rsqrtf(var + EPS_BN);
        float sc = gamma[t] * inv;
        sc_s[t] = sc;
        sh_s[t] = beta[t] - mean * sc;
    }
    __syncthreads();
    int i = blockIdx.x * 256 + t;
    int j4 = (i & 31) * 4;
    ushort4 hv = ((const ushort4*)H2)[i];
    float4 o;
    o.x = bf2f(hv.x) * sc_s[j4 + 0] + sh_s[j4 + 0];
    o.y = bf2f(hv.y) * sc_s[j4 + 1] + sh_s[j4 + 1];
    o.z = bf2f(hv.z) * sc_s[j4 + 2] + sh_s[j4 + 2];
    o.w = bf2f(hv.w) * sc_s[j4 + 3] + sh_s[j4 + 3];
    ((float4*)out)[i] = o;
}

// ---------------------------------------------------------------------------
extern "C" void kernel_launch(void* const* d_in, const int* in_sizes, int n_in,
                              void* d_out, int out_size, void* d_ws,
                              size_t ws_size, hipStream_t stream) {
    (void)in_sizes; (void)n_in; (void)out_size; (void)ws_size;
    const float* x     = (const float*)d_in[0];
    const void*  eidx  = d_in[1];
    const float* W1    = (const float*)d_in[2];
    const float* b1    = (const float*)d_in[3];
    const float* W2    = (const float*)d_in[4];
    const float* b2    = (const float*)d_in[5];
    const float* gamma = (const float*)d_in[6];
    const float* beta  = (const float*)d_in[7];
    float* out = (float*)d_out;

    char* p = (char*)d_ws;
    auto alloc = [&](size_t bytes) {
        char* r = p;
        p += (bytes + 255) & ~(size_t)255;
        return r;
    };
    unsigned short* h2bf = (unsigned short*)alloc((size_t)N_NODES * DIM * 2); // 25.6MB
    unsigned* slots = (unsigned*)alloc((size_t)NB * CAP * 4);                 // 8.4MB
    unsigned short* xb = (unsigned short*)alloc((size_t)N_NODES * DIM * 2);   // 25.6MB
    float* gpart  = (float*)alloc((size_t)NB * 256 * 4);                      // 1MB
    int*   bcur   = (int*)alloc(NB * 4 + 2 * DIM * 4);     // bcur + gstats adj
    float* gstats = (float*)(bcur + NB);
    unsigned short* W1t = (unsigned short*)alloc(DIM * DIM * 2);
    unsigned short* W2t = (unsigned short*)alloc(DIM * DIM * 2);

    hipMemsetAsync(bcur, 0, NB * 4 + 2 * DIM * 4, stream);
    bin_scatter_xw<<<NBLK, 1024, 0, stream>>>(eidx, bcur, slots, x, xb,
                                              W1, W2, W1t, W2t);
    csr_agg_mlp<<<NB, 1024, 0, stream>>>(xb, slots, bcur, W1t, W2t, b1, b2,
                                         h2bf, gpart);
    reduce_stats<<<32, 256, 0, stream>>>(gpart, gstats);
    bn_apply<<<(N_NODES * DIM / 4) / 256, 256, 0, stream>>>(h2bf, gstats,
                                                            gamma, beta, out);
}

// Round 10
// 263.349 us; speedup vs baseline: 1.7662x; 1.0027x over previous
//
#include <hip/hip_runtime.h>

#define N_NODES 100000
#define N_EDGES 1600000
#define DIM     128
#define EPS_BN  1e-5f
#define NB      1024     // buckets
#define NPB     98       // nodes per bucket (1024*98 = 100352 >= 100000)
#define NBLK    256      // bin_scatter blocks
#define EPB     6250     // edges per bin_scatter block (256*6250 == N_EDGES)
#define CAP     2048     // slot capacity per bucket (mean 1562.5, sigma~40)
#define PADR    112      // As rows (7 tiles of 16 >= NPB)
#define NT      7        // MFMA row-tiles per bucket
#define LPITCH  136      // LDS pitch in bf16 units (272B = 17*16B, b128-aligned)

typedef __attribute__((ext_vector_type(8))) short short8;
typedef __attribute__((ext_vector_type(4))) float floatx4;

__device__ __forceinline__ unsigned short f2bf(float f) {   // RNE bf16 bits
    unsigned u = __float_as_uint(f);
    return (unsigned short)((u + 0x7FFF + ((u >> 16) & 1)) >> 16);
}
__device__ __forceinline__ float bf2f(unsigned short b) {
    return __uint_as_float((unsigned)b << 16);
}

// int64 layout => odd int32 words all zero. Wave-uniform result.
__device__ __forceinline__ int detect64(const void* eidx) {
    int v = ((const int*)eidx)[2 * (threadIdx.x & 63) + 1];
    unsigned long long b = __ballot(v != 0);
    return (b == 0ULL) ? 1 : 0;
}
__device__ __forceinline__ int load_row(const void* eidx, int is64, int e) {
    if (is64) return (int)((const long long*)eidx)[e];
    return ((const int*)eidx)[e];
}
__device__ __forceinline__ int load_col(const void* eidx, int is64, int e) {
    if (is64) return (int)((const long long*)eidx)[N_EDGES + e];
    return ((const int*)eidx)[N_EDGES + e];
}

// ---------------------------------------------------------------------------
// bin_scatter_xw: 256 blocks x 1024 threads (round-9 proven). hist -> LDS
// scan (1024 buckets) -> per-bucket global range claim -> LDS bucket-sorted
// staging (packed 4B: row_local<<24 | col) -> LINEAR copy out. Blocks 0/1
// also transpose W1/W2 to bf16 [n][k]. Then grid-stride xconv.
// ---------------------------------------------------------------------------
__global__ __launch_bounds__(1024) void bin_scatter_xw(
    const void* eidx, int* bcur, unsigned* __restrict__ slots,
    const float* __restrict__ x, unsigned short* __restrict__ xb,
    const float* __restrict__ W1, const float* __restrict__ W2,
    unsigned short* __restrict__ W1t, unsigned short* __restrict__ W2t) {
    __shared__ int lh[NB];
    __shared__ int lbase[NB];
    __shared__ int loff[NB];
    __shared__ unsigned stage[EPB];
    __shared__ int gaddr[EPB];
    int t = threadIdx.x;
    int is64 = detect64(eidx);
    lh[t] = 0;
    __syncthreads();
    int base = blockIdx.x * EPB;
    for (int i = t; i < EPB; i += 1024) {
        int r = load_row(eidx, is64, base + i);
        atomicAdd(&lh[r / NPB], 1);
    }
    __syncthreads();
    // inclusive scan of lh[0..1023] into loff (1 elem/thread)
    loff[t] = lh[t];
    __syncthreads();
    for (int off = 1; off < NB; off <<= 1) {
        int a = (t >= off) ? loff[t - off] : 0;
        __syncthreads();
        loff[t] += a;
        __syncthreads();
    }
    // claim global ranges, make loff exclusive, reset lh for scatter cursors
    {
        int c = lh[t];
        lbase[t] = c ? atomicAdd(&bcur[t], c) : 0;
        loff[t] -= c;
        lh[t] = 0;
    }
    __syncthreads();
    for (int i = t; i < EPB; i += 1024) {
        int r = load_row(eidx, is64, base + i);
        int c = load_col(eidx, is64, base + i);
        int b = r / NPB;
        int pos = atomicAdd(&lh[b], 1);
        int idx = loff[b] + pos;
        int ga = lbase[b] + pos;
        if (ga >= CAP) ga = CAP - 1;          // clamp (never taken in practice)
        stage[idx] = ((unsigned)(r - b * NPB) << 24) | (unsigned)c;
        gaddr[idx] = b * CAP + ga;
    }
    __syncthreads();
    for (int i = t; i < EPB; i += 1024)       // linear: runs coalesce to lines
        slots[gaddr[i]] = stage[i];
    // ---- W transpose (blocks 0/1) ----
    if (blockIdx.x < 2) {
        const float* W = blockIdx.x ? W2 : W1;
        unsigned short* Wt = blockIdx.x ? W2t : W1t;
        for (int i = t; i < DIM * DIM; i += 1024) {
            int k = i >> 7, n = i & 127;
            Wt[n * DIM + k] = f2bf(W[i]);
        }
    }
    // ---- fused xconv: grid-stride f32 -> bf16 ----
    for (int i = blockIdx.x * 1024 + t; i < N_NODES * DIM / 4; i += NBLK * 1024) {
        float4 v = ((const float4*)x)[i];
        ushort4 o;
        o.x = f2bf(v.x); o.y = f2bf(v.y); o.z = f2bf(v.z); o.w = f2bf(v.w);
        ((ushort4*)xb)[i] = o;
    }
}

// ---------------------------------------------------------------------------
// csr_agg_mlp v2: one block (1024 thr) per bucket. (1) in-LDS sort; (2)
// 16-deep pipelined gather into As tile; (3) inline MLP with GEMM work
// spread over 14 wave-tasks (row-tile r x col-half h), acc[4] each --
// round-9's 7-wave version left the GEMM phase ~2x too long, starving the
// co-resident block's gather below the ~22-wave fabric knee. acc1 rides in
// registers across the barrier; relu writes (col-disjoint per h) + W2
// restage sit between the same two barriers as before.
// ---------------------------------------------------------------------------
__global__ __launch_bounds__(1024, 8) void csr_agg_mlp(
    const unsigned short* __restrict__ xb,
    const unsigned* __restrict__ slots,
    const int* __restrict__ bcnt,
    const unsigned short* __restrict__ B1t,
    const unsigned short* __restrict__ B2t,
    const float* __restrict__ bias1, const float* __restrict__ bias2,
    unsigned short* __restrict__ h2,         // N_NODES x 128 bf16
    float* __restrict__ gpart) {             // NB x 256 partials
    __shared__ int hist[128];
    __shared__ int incl[128];                 // inclusive scan (row ranges)
    __shared__ int cur[128];                  // scatter cursors
    __shared__ int colbuf[CAP];               // 8KB; reused as csum/csq later
    __shared__ unsigned short As[PADR * LPITCH];   // 30464 B
    __shared__ unsigned short Bs[DIM * LPITCH];    // 34816 B
    int t = threadIdx.x;
    int b = blockIdx.x;
    int lane = t & 63, wv = t >> 6;
    int m = lane & 15, g = lane >> 4;
    int cnt = bcnt[b];
    if (cnt > CAP) cnt = CAP;                 // clamp (never taken in practice)
    if (cnt < 0) cnt = 0;
    int node0 = b * NPB;
    int nn = N_NODES - node0;
    if (nn > NPB) nn = NPB;
    if (nn < 0) nn = 0;
    const unsigned* pairs = slots + (size_t)b * CAP;

    // stage W1 -> Bs (2 x uint4 per thread)
#pragma unroll
    for (int i = 0; i < 2; ++i) {
        int ch = t + 1024 * i;
        int n = ch >> 4, cc = ch & 15;
        *(uint4*)(&Bs[n * LPITCH + cc * 8]) =
            *(const uint4*)(&B1t[n * DIM + cc * 8]);
    }
    if (t < 128) hist[t] = 0;
    __syncthreads();
    for (int i = t; i < cnt; i += 1024)
        atomicAdd(&hist[(int)(pairs[i] >> 24)], 1);
    __syncthreads();
    int v = (t < 128) ? hist[t] : 0;
    if (t < 128) incl[t] = v;
    __syncthreads();
    for (int off = 1; off < 128; off <<= 1) {
        int a = (t >= off && t < 128) ? incl[t - off] : 0;
        __syncthreads();
        if (t < 128) incl[t] += a;
        __syncthreads();
    }
    if (t < 128) cur[t] = incl[t] - v;        // exclusive start
    __syncthreads();
    for (int i = t; i < cnt; i += 1024) {
        unsigned pr = pairs[i];
        int pos = atomicAdd(&cur[pr >> 24], 1);
        if (pos < CAP) colbuf[pos] = (int)(pr & 0xFFFFFFu);
    }
    __syncthreads();

    // ---- aggregation straight off LDS lists into As (16 waves, 7 rows ea) ----
    const unsigned* xbw = (const unsigned*)xb;    // 64 words per row
    for (int nl = wv; nl < PADR; nl += 16) {
        unsigned pack = 0u;
        if (nl < nn) {
            int node = node0 + nl;
            unsigned selfw = xbw[(size_t)node * 64 + lane];
            float ax = __uint_as_float(selfw << 16);
            float ay = __uint_as_float(selfw & 0xffff0000u);
            int e = incl[nl];
            int s = nl ? incl[nl - 1] : 0;
            s = __builtin_amdgcn_readfirstlane(s);
            e = __builtin_amdgcn_readfirstlane(e);
            int d = e - s;
            if (d <= 16) {
                unsigned pw[16];
#pragma unroll
                for (int u = 0; u < 16; ++u) {
                    int idx = s + u;
                    int ci = (idx < e) ? idx : s;      // clamp: dup row, L1 hit
                    pw[u] = xbw[(size_t)colbuf[ci] * 64 + lane];
                }
#pragma unroll
                for (int u = 0; u < 16; ++u) {
                    unsigned w = (u < d) ? pw[u] : 0u; // masked accumulate
                    ax += __uint_as_float(w << 16);
                    ay += __uint_as_float(w & 0xffff0000u);
                }
            } else {
                int j = s;
                for (; j + 16 <= e; j += 16) {
                    unsigned pw[16];
#pragma unroll
                    for (int u = 0; u < 16; ++u)
                        pw[u] = xbw[(size_t)colbuf[j + u] * 64 + lane];
#pragma unroll
                    for (int u = 0; u < 16; ++u) {
                        ax += __uint_as_float(pw[u] << 16);
                        ay += __uint_as_float(pw[u] & 0xffff0000u);
                    }
                }
                if (j < e) {
                    unsigned pw[16];
                    int dd = e - j;
#pragma unroll
                    for (int u = 0; u < 16; ++u) {
                        int idx = j + u;
                        int ci = (idx < e) ? idx : s;
                        pw[u] = xbw[(size_t)colbuf[ci] * 64 + lane];
                    }
#pragma unroll
                    for (int u = 0; u < 16; ++u) {
                        unsigned w = (u < dd) ? pw[u] : 0u;
                        ax += __uint_as_float(w << 16);
                        ay += __uint_as_float(w & 0xffff0000u);
                    }
                }
            }
            pack = (unsigned)f2bf(ax) | ((unsigned)f2bf(ay) << 16);
        }
        *(unsigned*)(&As[nl * LPITCH + lane * 2]) = pack;   // pad rows: zero
    }
    __syncthreads();

    // ---- GEMM1: 14 wave-tasks (row-tile rT, col-half hT), acc 4 tiles ----
    int rT = wv >> 1, hT = wv & 1;
    bool act = (wv < 2 * NT);
    floatx4 acc1[4];
    if (act) {
#pragma unroll
        for (int q = 0; q < 4; ++q) acc1[q] = (floatx4){0.f, 0.f, 0.f, 0.f};
#pragma unroll
        for (int kc = 0; kc < 4; ++kc) {
            short8 a = *(const short8*)(&As[(rT * 16 + m) * LPITCH + kc * 32 + g * 8]);
#pragma unroll
            for (int q = 0; q < 4; ++q) {
                int tile = hT * 4 + q;
                short8 bb = *(const short8*)(&Bs[(tile * 16 + m) * LPITCH + kc * 32 + g * 8]);
                acc1[q] = __builtin_amdgcn_mfma_f32_16x16x32_bf16(a, bb, acc1[q], 0, 0, 0);
            }
        }
    }
    __syncthreads();                          // all As/Bs reads of GEMM1 done

    // relu -> As (cols owned by (rT,hT)); stage W2 -> Bs; zero stats
    if (act) {
#pragma unroll
        for (int q = 0; q < 4; ++q) {
            int col = (hT * 4 + q) * 16 + m;
            float bv = bias1[col];
#pragma unroll
            for (int j = 0; j < 4; ++j) {
                int rl = rT * 16 + g * 4 + j;
                As[rl * LPITCH + col] = f2bf(fmaxf(acc1[q][j] + bv, 0.f));
            }
        }
    }
#pragma unroll
    for (int i = 0; i < 2; ++i) {
        int ch = t + 1024 * i;
        int n = ch >> 4, cc = ch & 15;
        *(uint4*)(&Bs[n * LPITCH + cc * 8]) =
            *(const uint4*)(&B2t[n * DIM + cc * 8]);
    }
    float* csum = (float*)colbuf;             // colbuf dead after agg phase
    if (t < 256) csum[t] = 0.f;               // [0..127]=sum, [128..255]=sq
    __syncthreads();

    // ---- GEMM2: same 14-task split ----
    if (act) {
        floatx4 acc2[4];
#pragma unroll
        for (int q = 0; q < 4; ++q) acc2[q] = (floatx4){0.f, 0.f, 0.f, 0.f};
#pragma unroll
        for (int kc = 0; kc < 4; ++kc) {
            short8 a = *(const short8*)(&As[(rT * 16 + m) * LPITCH + kc * 32 + g * 8]);
#pragma unroll
            for (int q = 0; q < 4; ++q) {
                int tile = hT * 4 + q;
                short8 bb = *(const short8*)(&Bs[(tile * 16 + m) * LPITCH + kc * 32 + g * 8]);
                acc2[q] = __builtin_amdgcn_mfma_f32_16x16x32_bf16(a, bb, acc2[q], 0, 0, 0);
            }
        }
#pragma unroll
        for (int q = 0; q < 4; ++q) {
            int col = (hT * 4 + q) * 16 + m;
            float bv = bias2[col];
            float s = 0.f, qq = 0.f;
#pragma unroll
            for (int j = 0; j < 4; ++j) {
                int rl = rT * 16 + g * 4 + j;
                if (rl < nn) {
                    float vv = acc2[q][j] + bv;
                    h2[(size_t)(node0 + rl) * DIM + col] = f2bf(vv);
                    s += vv; qq += vv * vv;
                }
            }
            atomicAdd(&csum[col], s);
            atomicAdd(&csum[DIM + col], qq);
        }
    }
    __syncthreads();
    if (t < 256) gpart[(size_t)b * 256 + t] = csum[t];
}

// ---------------------------------------------------------------------------
// Reduce NB x 256 partials -> gstats[256].
// ---------------------------------------------------------------------------
__global__ __launch_bounds__(256) void reduce_stats(
    const float* __restrict__ gpart, float* __restrict__ gstats) {
    int t = threadIdx.x;
    int chunk = NB / 32;                      // 32
    int r0 = blockIdx.x * chunk;
    float s = 0.f;
    for (int r = r0; r < r0 + chunk; ++r) s += gpart[(size_t)r * 256 + t];
    atomicAdd(&gstats[t], s);
}

// ---------------------------------------------------------------------------
// BN finalize (redundant per block) + apply.
// ---------------------------------------------------------------------------
__global__ __launch_bounds__(256) void bn_apply(
    const unsigned short* __restrict__ H2, const float* __restrict__ gstats,
    const float* __restrict__ gamma, const float* __restrict__ beta,
    float* __restrict__ out) {
    __shared__ float sc_s[DIM], sh_s[DIM];
    int t = threadIdx.x;
    if (t < DIM) {
        float mean = gstats[t] * (1.0f / N_NODES);
        float m2 = gstats[DIM + t] * (1.0f / N_NODES);
        float var = m2 - mean * mean;
        float inv = rsqrtf(var + EPS_BN);
        float sc = gamma[t] * inv;
        sc_s[t] = sc;
        sh_s[t] = beta[t] - mean * sc;
    }
    __syncthreads();
    int i = blockIdx.x * 256 + t;
    int j4 = (i & 31) * 4;
    ushort4 hv = ((const ushort4*)H2)[i];
    float4 o;
    o.x = bf2f(hv.x) * sc_s[j4 + 0] + sh_s[j4 + 0];
    o.y = bf2f(hv.y) * sc_s[j4 + 1] + sh_s[j4 + 1];
    o.z = bf2f(hv.z) * sc_s[j4 + 2] + sh_s[j4 + 2];
    o.w = bf2f(hv.w) * sc_s[j4 + 3] + sh_s[j4 + 3];
    ((float4*)out)[i] = o;
}

// ---------------------------------------------------------------------------
extern "C" void kernel_launch(void* const* d_in, const int* in_sizes, int n_in,
                              void* d_out, int out_size, void* d_ws,
                              size_t ws_size, hipStream_t stream) {
    (void)in_sizes; (void)n_in; (void)out_size; (void)ws_size;
    const float* x     = (const float*)d_in[0];
    const void*  eidx  = d_in[1];
    const float* W1    = (const float*)d_in[2];
    const float* b1    = (const float*)d_in[3];
    const float* W2    = (const float*)d_in[4];
    const float* b2    = (const float*)d_in[5];
    const float* gamma = (const float*)d_in[6];
    const float* beta  = (const float*)d_in[7];
    float* out = (float*)d_out;

    char* p = (char*)d_ws;
    auto alloc = [&](size_t bytes) {
        char* r = p;
        p += (bytes + 255) & ~(size_t)255;
        return r;
    };
    unsigned short* h2bf = (unsigned short*)alloc((size_t)N_NODES * DIM * 2); // 25.6MB
    unsigned* slots = (unsigned*)alloc((size_t)NB * CAP * 4);                 // 8.4MB
    unsigned short* xb = (unsigned short*)alloc((size_t)N_NODES * DIM * 2);   // 25.6MB
    float* gpart  = (float*)alloc((size_t)NB * 256 * 4);                      // 1MB
    int*   bcur   = (int*)alloc(NB * 4 + 2 * DIM * 4);     // bcur + gstats adj
    float* gstats = (float*)(bcur + NB);
    unsigned short* W1t = (unsigned short*)alloc(DIM * DIM * 2);
    unsigned short* W2t = (unsigned short*)alloc(DIM * DIM * 2);

    hipMemsetAsync(bcur, 0, NB * 4 + 2 * DIM * 4, stream);
    bin_scatter_xw<<<NBLK, 1024, 0, stream>>>(eidx, bcur, slots, x, xb,
                                              W1, W2, W1t, W2t);
    csr_agg_mlp<<<NB, 1024, 0, stream>>>(xb, slots, bcur, W1t, W2t, b1, b2,
                                         h2bf, gpart);
    reduce_stats<<<32, 256, 0, stream>>>(gpart, gstats);
    bn_apply<<<(N_NODES * DIM / 4) / 256, 256, 0, stream>>>(h2bf, gstats,
                                                            gamma, beta, out);
}